// Round 15
// baseline (368.326 us; speedup 1.0000x reference)
//
#include <hip/hip_runtime.h>
#include <hip/hip_bf16.h>

// Round 25: knn lane-utilization fix — flattened multi-segment ball walk.
//  - scan & seed-collect previously iterated (x,y) columns serially with ~8/64
//    lanes active (z-runs are ~4-16 pts). Now: per 64-column chunk, wave
//    prefix-scan of run lengths -> dense g->lane assignment; column lookup via
//    6-step bpermute binary search over register-held prefixes. Same cells,
//    same float math, order-independent keys -> exact top-16 unchanged.
//    Seed subset ordering differs (column-order vs center-first) but any
//    >=16-pt subset gives a certified tau -> output identical.
// Everything else byte-identical to R24 (passing, 355.9us).

#define EPS 1e-5f

constexpr int Bb   = 8;
constexpr int Np   = 8192;
constexpr int Mq   = 2048;
constexpr int COUT = 128;
constexpr int BM   = Bb * Mq;        // 16384
constexpr int BMK  = BM * 16;        // 262144
constexpr int GC   = 16;
constexpr int NC   = GC * GC * GC;   // 4096
constexpr int CAP  = 320;            // candidate buffer per query (8B each)
constexpr int TS   = 20;             // Tst row stride (floats); 80B, 16B-aligned

typedef __attribute__((ext_vector_type(8))) short short8;
typedef __attribute__((ext_vector_type(4))) float f32x4;

__device__ __forceinline__ unsigned short f2bf(float x) {
  unsigned u = __float_as_uint(x);
  u += 0x7fffu + ((u >> 16) & 1u);
  return (unsigned short)(u >> 16);
}
__device__ __forceinline__ float bf2f_lo(unsigned v) { return __uint_as_float(v << 16); }
__device__ __forceinline__ float bf2f_hi(unsigned v) { return __uint_as_float(v & 0xffff0000u); }
__device__ __forceinline__ float bfround(float x) {
  return __uint_as_float(((unsigned)f2bf(x)) << 16);
}

__device__ __forceinline__ int cell_of(float c) {
  int v = (int)floorf(c * 2.0f + 8.0f);
  return v < 0 ? 0 : (v > 15 ? 15 : v);
}

__device__ __forceinline__ unsigned enc_dist(float d) {
  unsigned uu = __float_as_uint(d);
  return uu ^ (((unsigned)(((int)uu) >> 31)) | 0x80000000u);
}

// ascending 64-lane bitonic sort of u64 keys
__device__ __forceinline__ void bsort64(unsigned long long& v, int lane) {
#pragma unroll
  for (int k = 2; k <= 64; k <<= 1) {
#pragma unroll
    for (int jj = k >> 1; jj > 0; jj >>= 1) {
      unsigned long long o = __shfl_xor(v, jj);
      bool keepMin = (((lane & k) == 0) == ((lane & jj) == 0));
      unsigned long long mn = v < o ? v : o;
      unsigned long long mx = v < o ? o : v;
      v = keepMin ? mn : mx;
    }
  }
}
// ascending merge of a bitonic 64-lane sequence
__device__ __forceinline__ void bmerge64(unsigned long long& v, int lane) {
#pragma unroll
  for (int jj = 32; jj > 0; jj >>= 1) {
    unsigned long long o = __shfl_xor(v, jj);
    bool keepMin = ((lane & jj) == 0);
    unsigned long long mn = v < o ? v : o;
    unsigned long long mx = v < o ? o : v;
    v = keepMin ? mn : mx;
  }
}
// sorted (ascending) smallest-64 keys of buf[0..C)
__device__ __forceinline__ unsigned long long sort_smallest64(const unsigned long long* buf,
                                                              int C, int lane) {
  unsigned long long run = (lane < C) ? buf[lane] : ~0ULL;
  bsort64(run, lane);
  for (int b2 = 64; b2 < C; b2 += 64) {
    unsigned long long v = (b2 + lane < C) ? buf[b2 + lane] : ~0ULL;
    bsort64(v, lane);
    unsigned long long vr = __shfl_xor(v, 63);  // reverse -> descending
    unsigned long long m = run < vr ? run : vr; // bitonic, contains smallest 64
    bmerge64(m, lane);
    run = m;
  }
  return run;
}

// stats float offsets: s1(9)@0, s2(64)@16, spt1(512)@128, spt2(512)@640, spout(256)@1152

__device__ __forceinline__ void bn1_compute(int o, const float* __restrict__ st,
                                            const float* __restrict__ W1,
                                            const float* __restrict__ b1,
                                            const float* __restrict__ g1,
                                            const float* __restrict__ be1,
                                            float* sc_out, float* shf_out) {
  float n = (float)BMK;
  float w0 = W1[3 * o], w1 = W1[3 * o + 1], w2 = W1[3 * o + 2], b = b1[o];
  float s0 = st[0], s1 = st[1], s2 = st[2];
  float m00 = st[3], m11 = st[4], m22 = st[5], m01 = st[6], m02 = st[7], m12 = st[8];
  float ws = (w0 * s0 + w1 * s1 + w2 * s2) / n;
  float mean = b + ws;
  float quad = w0 * w0 * m00 + w1 * w1 * m11 + w2 * w2 * m22 +
               2.f * (w0 * w1 * m01 + w0 * w2 * m02 + w1 * w2 * m12);
  float ex2 = quad / n + 2.f * b * ws + b * b;
  float var = ex2 - mean * mean;
  float sc = g1[o] * rsqrtf(var + EPS);
  *sc_out = sc;
  *shf_out = be1[o] - mean * sc + b * sc;
}

// ---------------- fused prep: pack pts (+cell histogram) | transpose x | Wc repack
//                  | Ws1 hi/lo repack | q-copy into dout
__global__ __launch_bounds__(256) void prep_kernel(const float* __restrict__ p,
                                                   const float* __restrict__ x,
                                                   const float* __restrict__ Wc,
                                                   const float* __restrict__ Ws1,
                                                   const float* __restrict__ q,
                                                   float4* __restrict__ pp4,
                                                   float* __restrict__ xt,
                                                   unsigned short* __restrict__ wcrp,
                                                   unsigned short* __restrict__ ws1r,
                                                   int* __restrict__ hist,
                                                   float* __restrict__ dout) {
  __shared__ float tile[64][65];
  int blk = blockIdx.x;
  int tid = threadIdx.x;
  if (blk < 256) {
    int i = blk * 256 + tid;  // < 65536
    float px = p[3 * i], py = p[3 * i + 1], pz = p[3 * i + 2];
    float pp = __fadd_rn(__fadd_rn(__fmul_rn(px, px), __fmul_rn(py, py)), __fmul_rn(pz, pz));
    pp4[i] = make_float4(px, py, pz, pp);
    int b = i >> 13;
    int cid = (cell_of(px) << 8) | (cell_of(py) << 4) | cell_of(pz);
    atomicAdd(&hist[b * NC + cid], 1);
  } else if (blk < 1280) {
    int bx = blk - 256;
    int b = bx >> 7;
    int n0 = (bx & 127) << 6;
    int nl = tid & 63;
    int r0 = tid >> 6;
    const float* xb = x + (size_t)b * 64 * Np;
    for (int c = r0; c < 64; c += 4) tile[c][nl] = xb[(size_t)c * Np + n0 + nl];
    __syncthreads();
    float* xtb = xt + (size_t)b * Np * 64;
    for (int n = r0; n < 64; n += 4) xtb[(size_t)(n0 + n) * 64 + nl] = tile[nl][n];
  } else if (blk < 2048) {
    int g = (blk - 1280) * 256 + tid;
    if (g < 128 * 1536) {
      int o = g / 1536, r = g % 1536;
      int c = r % 96, j = r / 96;
      wcrp[g] = f2bf(Wc[(size_t)o * 1536 + c * 16 + j]);
    }
  } else if (blk < 2112) {
    int g = (blk - 2048) * 256 + tid;  // < 16384 : (o, i) with i = k*3+c
    int o = g >> 6, i = g & 63;
    float val = 0.f;
    if (i < 48) {
      int k = i / 3, c = i - 3 * k;
      val = Ws1[(size_t)o * 48 + c * 16 + k];
    }
    unsigned short h = f2bf(val);
    float hf = __uint_as_float(((unsigned)h) << 16);
    unsigned short l = f2bf(val - hf);
    ws1r[g] = h;
    ws1r[16384 + g] = l;
  } else {
    int g = (blk - 2112) * 256 + tid;  // < 49152 = BM*3
    dout[g] = q[g];
  }
}

// ---------------- exclusive prefix over 4096 cells per batch
__global__ __launch_bounds__(256) void prefix_kernel(const int* __restrict__ hist,
                                                     int* __restrict__ cellstart,
                                                     int* __restrict__ cursor) {
  __shared__ int ls[256];
  int b = blockIdx.x, t = threadIdx.x;
  const int* h = hist + b * NC;
  int loc[16], s = 0;
#pragma unroll
  for (int k = 0; k < 16; ++k) { loc[k] = h[t * 16 + k]; s += loc[k]; }
  ls[t] = s;
  __syncthreads();
  for (int off = 1; off < 256; off <<= 1) {
    int v = (t >= off) ? ls[t - off] : 0;
    __syncthreads();
    ls[t] += v;
    __syncthreads();
  }
  int run = ls[t] - s;
  int* cs = cellstart + b * (NC + 1);
  int* cu = cursor + b * NC;
#pragma unroll
  for (int k = 0; k < 16; ++k) {
    cs[t * 16 + k] = run;
    cu[t * 16 + k] = run;
    run += loc[k];
  }
  if (t == 255) cs[NC] = run;
}

// ---------------- scatter points into cell-sorted arrays
__global__ __launch_bounds__(256) void scatter_kernel(const float4* __restrict__ pp4,
                                                      int* __restrict__ cursor,
                                                      float4* __restrict__ sp4,
                                                      int* __restrict__ sidx) {
  int i = blockIdx.x * 256 + threadIdx.x;  // < 65536
  int b = i >> 13;
  float4 pv = pp4[i];
  int cid = (cell_of(pv.x) << 8) | (cell_of(pv.y) << 4) | cell_of(pv.z);
  int pos = atomicAdd(&cursor[b * NC + cid], 1);
  sp4[(size_t)b * Np + pos] = pv;
  sidx[(size_t)b * Np + pos] = i & 8191;
}

// ---------------- kNN: one query per 64-thread block; flattened segment walk
__global__ __launch_bounds__(64) void knn_kernel(const float4* __restrict__ pp4,
                                                 const float4* __restrict__ sp4,
                                                 const int* __restrict__ sidx,
                                                 const int* __restrict__ cellstart,
                                                 const float* __restrict__ q,
                                                 int* __restrict__ idx_out,
                                                 float* __restrict__ phat) {
  __shared__ unsigned long long cand[CAP];  // one query per block
  int lane = threadIdx.x;
  int qi = blockIdx.x;  // 0..16383
  int b = qi >> 11;
  const float4* pb = pp4 + (size_t)b * Np;
  const float4* sp = sp4 + (size_t)b * Np;
  const int* sx = sidx + (size_t)b * Np;
  const int* cs = cellstart + b * (NC + 1);
  const float* qp = q + (size_t)qi * 3;
  float qx = qp[0], qy = qp[1], qz = qp[2];
  float qqv = __fadd_rn(__fadd_rn(__fmul_rn(qx, qx), __fmul_rn(qy, qy)), __fmul_rn(qz, qz));
  float tau_f = INFINITY;

  // ---- seed tau: smallest cell-cube with >=16 points; flattened collect of
  //      first <=128 points (column order); bisect encoded-distance bits.
  //      ANY >=16-pt subset yields a certified upper bound on the true 16th.
  {
    int cx = cell_of(qx), cy = cell_of(qy), cz = cell_of(qz);
    int alo = 0, blo = 0, nbw = 1, ncols = 1, zlo = 0, zhi = 0;
    for (int r = 0;; ++r) {
      alo = cx - r; if (alo < 0) alo = 0;
      int ahi = cx + r; if (ahi > 15) ahi = 15;
      blo = cy - r; if (blo < 0) blo = 0;
      int bhi = cy + r; if (bhi > 15) bhi = 15;
      zlo = cz - r; if (zlo < 0) zlo = 0;
      zhi = cz + r; if (zhi > 15) zhi = 15;
      nbw = bhi - blo + 1;
      ncols = (ahi - alo + 1) * nbw;
      int total = 0;
      for (int l0 = 0; l0 < ncols; l0 += 64) {
        int l = l0 + lane;
        int sL = 0, eL = 0;
        if (l < ncols) {
          int da = l / nbw, db = l - da * nbw;
          int cbase = ((alo + da) << 8) | ((blo + db) << 4);
          sL = cs[cbase + zlo];
          eL = cs[cbase + zhi + 1];  // prefix is contiguous across z
        }
        total += eL - sL;
      }
#pragma unroll
      for (int o = 32; o > 0; o >>= 1) total += __shfl_xor(total, o);
      if (total >= 16 || r >= 15) break;
    }
    // flattened collect (cap 128): per 64-column chunk, prefix-scan run
    // lengths; dense g->lane; column lookup via bpermute binary search.
    unsigned u0 = 0xFFFFFFFFu, u1 = 0xFFFFFFFFu;
    int wcnt = 0;
    for (int c0 = 0; c0 < ncols && wcnt < 128; c0 += 64) {
      int c = c0 + lane;
      int sL = 0, len = 0;
      if (c < ncols) {
        int da = c / nbw, db = c - da * nbw;
        int cbase = ((alo + da) << 8) | ((blo + db) << 4);
        sL = cs[cbase + zlo];
        len = cs[cbase + zhi + 1] - sL;
      }
      int pre = len;
#pragma unroll
      for (int o = 1; o < 64; o <<= 1) { int v = __shfl_up(pre, o); if (lane >= o) pre += v; }
      int ctot = __shfl(pre, 63);
      int myPre = pre - len;
      int take = ctot; if (take > 128 - wcnt) take = 128 - wcnt;
      for (int g0 = 0; g0 < take; g0 += 64) {
        int g = g0 + lane;
        bool valid = g < take;
        int gq = valid ? g : 0;
        int loi = 0;
#pragma unroll
        for (int st = 32; st > 0; st >>= 1) {
          int c2 = loi + st;
          int v = __shfl(myPre, c2 & 63);
          if (c2 < 64 && v <= gq) loi = c2;
        }
        int pos = __shfl(sL, loi) + (gq - __shfl(myPre, loi));
        if (valid) {
          float4 pv = sp[pos];
          float ee = __fmaf_rn(qz, pv.z, __fmaf_rn(qy, pv.y, __fmul_rn(qx, pv.x)));
          float d = __fadd_rn(__fsub_rn(qqv, __fmul_rn(2.0f, ee)), pv.w);
          unsigned uu = enc_dist(d);
          int gg = wcnt + g;
          if (gg < 64) u0 = uu; else u1 = uu;
        }
      }
      wcnt += take;
    }
    // bisection: invariant count(<= hi) >= 16 holds at EVERY iteration ->
    // hi is a certified upper bound (14 iters: <2.2% value slack).
    unsigned lo = 0u, hi = 0xFF800000u;
    for (int it = 0; it < 14; ++it) {
      unsigned mid = lo + ((hi - lo) >> 1);
      int c = (int)__popcll(__ballot(u0 <= mid)) + (int)__popcll(__ballot(u1 <= mid));
      if (c >= 16) hi = mid; else lo = mid + 1;
    }
    tau_f = (hi >= 0x80000000u) ? __uint_as_float(hi ^ 0x80000000u)
                                : __uint_as_float(~hi);
  }

  // ---- main scan: flattened walk of cells intersecting the certified ball.
  //      Same cells, same float math; keys (enc_d<<32|idx) order-independent
  //      -> bit-identical selection.
  int cnt = 0;
  unsigned long long lanebelow = (1ULL << lane) - 1ULL;
  {
    float R = sqrtf(fmaxf(tau_f, 0.f) + 3e-5f) * 1.0005f;
    int ax0 = cell_of(qx - R), ax1 = cell_of(qx + R);
    int ay0 = cell_of(qy - R), ay1 = cell_of(qy + R);
    int az0 = cell_of(qz - R), az1 = cell_of(qz + R);
    int nby = ay1 - ay0 + 1;
    int ncols = (ax1 - ax0 + 1) * nby;
    for (int c0 = 0; c0 < ncols; c0 += 64) {
      int c = c0 + lane;
      int sL = 0, len = 0;
      if (c < ncols) {
        int da = c / nby, db = c - da * nby;
        int cbase = ((ax0 + da) << 8) | ((ay0 + db) << 4);
        sL = cs[cbase + az0];
        len = cs[cbase + az1 + 1] - sL;
      }
      int pre = len;
#pragma unroll
      for (int o = 1; o < 64; o <<= 1) { int v = __shfl_up(pre, o); if (lane >= o) pre += v; }
      int ctot = __shfl(pre, 63);
      int myPre = pre - len;
      for (int g0 = 0; g0 < ctot; g0 += 64) {
        int g = g0 + lane;
        bool valid = g < ctot;
        int gq = valid ? g : 0;
        int loi = 0;
#pragma unroll
        for (int st = 32; st > 0; st >>= 1) {
          int c2 = loi + st;
          int v = __shfl(myPre, c2 & 63);
          if (c2 < 64 && v <= gq) loi = c2;
        }
        int pos = __shfl(sL, loi) + (gq - __shfl(myPre, loi));
        int posc = valid ? pos : 0;
        float4 pv = sp[posc];
        float ee = __fmaf_rn(qz, pv.z, __fmaf_rn(qy, pv.y, __fmul_rn(qx, pv.x)));
        float d = __fadd_rn(__fsub_rn(qqv, __fmul_rn(2.0f, ee)), pv.w);
        if (!valid) d = __uint_as_float(0x7FC00000u);  // NaN fails d<=tau
        unsigned long long mask = __ballot(d <= tau_f);
        if (mask) {
          if (d <= tau_f) {
            int oi = sx[posc];
            unsigned uu = enc_dist(d);
            int wp = cnt + (int)__popcll(mask & lanebelow);
            if (wp < CAP)
              cand[wp] = (((unsigned long long)uu) << 32) | (unsigned)oi;
          }
          cnt += (int)__popcll(mask);
        }
      }
    }
  }

  // ---- exact selection: sorted smallest-64 of candidates; lanes 0..15 emit
  unsigned long long key16 = ~0ULL;
  if (cnt <= CAP) {
    key16 = sort_smallest64(&cand[0], cnt, lane);
  } else {
    // rare fallback: verified R11 serial-insertion scan for this query
    unsigned long long kk = ~0ULL;
    float tl = tau_f;
    for (int base = 0; base < Np; base += 64) {
      float4 pv = pb[base + lane];
      float ee = __fmaf_rn(qz, pv.z, __fmaf_rn(qy, pv.y, __fmul_rn(qx, pv.x)));
      float dv = __fadd_rn(__fsub_rn(qqv, __fmul_rn(2.0f, ee)), pv.w);
      unsigned long long mask = __ballot(dv <= tl);
      if (mask) {
        unsigned uu = enc_dist(dv);
        unsigned long long cd = (((unsigned long long)uu) << 32) | (unsigned)(base + lane);
        do {
          int src = __ffsll((unsigned long long)mask) - 1;
          mask &= mask - 1;
          unsigned long long ck = __shfl(cd, src);
          unsigned long long up = __shfl_up(kk, 1);
          if (lane == 0) up = 0ULL;
          if (lane < 16 && ck < kk) kk = (up > ck) ? up : ck;
        } while (mask);
        unsigned long long tt = __shfl(kk, 15);
        unsigned tm = (unsigned)(tt >> 32);
        unsigned inv2 = tm ^ ((tm & 0x80000000u) ? 0x80000000u : 0xFFFFFFFFu);
        float tc = (tm == 0xFFFFFFFFu) ? INFINITY : __uint_as_float(inv2);
        if (tc < tl) tl = tc;
      }
    }
    key16 = kk;
  }
  if (lane < 16) {
    int oi = (int)(key16 & 0xffffffffULL);
    idx_out[(size_t)qi * 16 + lane] = oi;
    // fused phat gather: same floats, same subtraction as old phat_stats
    float4 pv = pb[oi];
    float h0 = pv.x - qx, h1 = pv.y - qy, h2 = pv.z - qz;
    size_t base3 = ((size_t)qi * 16 + lane) * 3;
    phat[base3 + 0] = h0;
    phat[base3 + 1] = h1;
    phat[base3 + 2] = h2;
  }
}

// ---------------- accumulate 9 phat moments (linear reads; gather now in knn)
__global__ __launch_bounds__(256) void phat_stats_kernel(const float* __restrict__ phat,
                                                         float* __restrict__ stats) {
  float a[9];
#pragma unroll
  for (int k = 0; k < 9; ++k) a[k] = 0.f;
  int tid = threadIdx.x;
  for (int it = 0; it < 4; ++it) {
    int bmk = blockIdx.x * 256 + tid + it * 65536;
    float h0 = phat[(size_t)bmk * 3 + 0];
    float h1 = phat[(size_t)bmk * 3 + 1];
    float h2 = phat[(size_t)bmk * 3 + 2];
    a[0] += h0; a[1] += h1; a[2] += h2;
    a[3] += h0 * h0; a[4] += h1 * h1; a[5] += h2 * h2;
    a[6] += h0 * h1; a[7] += h0 * h2; a[8] += h1 * h2;
  }
#pragma unroll
  for (int off = 32; off > 0; off >>= 1)
#pragma unroll
    for (int k = 0; k < 9; ++k) a[k] += __shfl_down(a[k], off);
  __shared__ float ls[9];
  if (tid < 9) ls[tid] = 0.f;
  __syncthreads();
  if ((tid & 63) == 0)
    for (int k = 0; k < 9; ++k) atomicAdd(&ls[k], a[k]);
  __syncthreads();
  if (tid < 9) atomicAdd(&stats[tid], ls[tid]);
}

// ---------------- pre2 channel stats, two-phase through LDS
__global__ __launch_bounds__(256) void stats2_kernel(const float* __restrict__ phat,
                                                     const float* __restrict__ stats,
                                                     const float* __restrict__ W1,
                                                     const float* __restrict__ b1,
                                                     const float* __restrict__ g1,
                                                     const float* __restrict__ be1,
                                                     const float* __restrict__ W2,
                                                     const float* __restrict__ b2,
                                                     float* __restrict__ stats2) {
  __shared__ float hsh[256 * 36];
  __shared__ float w2s[32 * 33];
  __shared__ float w1s[96], sc1[32], sh1[32], b2s[32], ls[64];
  int tid = threadIdx.x;
  if (tid < 32) {
    bn1_compute(tid, stats, W1, b1, g1, be1, &sc1[tid], &sh1[tid]);
    b2s[tid] = b2[tid];
  }
  if (tid < 96) w1s[tid] = W1[tid];
  if (tid < 64) ls[tid] = 0.f;
  for (int e = tid; e < 1024; e += 256) w2s[(e >> 5) * 33 + (e & 31)] = W2[e];
  __syncthreads();
  {
    int bmk = blockIdx.x * 256 + tid;
    float h0 = phat[(size_t)bmk * 3], hy = phat[(size_t)bmk * 3 + 1], hz = phat[(size_t)bmk * 3 + 2];
#pragma unroll
    for (int o4 = 0; o4 < 8; ++o4) {
      float4 r;
      float* rp = (float*)&r;
#pragma unroll
      for (int u = 0; u < 4; ++u) {
        int o = o4 * 4 + u;
        float t = w1s[3 * o] * h0 + w1s[3 * o + 1] * hy + w1s[3 * o + 2] * hz;
        rp[u] = fmaxf(0.f, t * sc1[o] + sh1[o]);
      }
      *(float4*)&hsh[tid * 36 + o4 * 4] = r;
    }
  }
  __syncthreads();
  int oc = tid & 31, grp = tid >> 5;
  float wrow[32];
#pragma unroll
  for (int c = 0; c < 32; ++c) wrow[c] = w2s[oc * 33 + c];
  float bias = b2s[oc];
  float ss = 0.f, qq = 0.f;
  for (int r = 0; r < 32; ++r) {
    int row = grp * 32 + r;
    float a = bias;
    const float4* hr = (const float4*)&hsh[row * 36];
#pragma unroll
    for (int c4 = 0; c4 < 8; ++c4) {
      float4 hv = hr[c4];
      a += hv.x * wrow[c4 * 4 + 0];
      a += hv.y * wrow[c4 * 4 + 1];
      a += hv.z * wrow[c4 * 4 + 2];
      a += hv.w * wrow[c4 * 4 + 3];
    }
    ss += a;
    qq += a * a;
  }
  atomicAdd(&ls[oc], ss);
  atomicAdd(&ls[32 + oc], qq);
  __syncthreads();
  if (tid < 64) atomicAdd(&stats2[tid], ls[tid]);
}

// ---------------- stn1: pt1 = phat @ ws1r^T via bf16x2 (hi/lo) MFMA + fused stats
__global__ __launch_bounds__(256) void stn1_kernel(const float* __restrict__ phat,
                                                   const unsigned short* __restrict__ ws1r,
                                                   const float* __restrict__ bs1,
                                                   float* __restrict__ pt1,
                                                   float* __restrict__ spt1) {
  __shared__ unsigned short Ah[64 * 72], Al[64 * 72], Bh[128 * 72], Bl[128 * 72];
  __shared__ float ls[256];
  int tid = threadIdx.x;
  ls[tid] = 0.f;
  int mb = blockIdx.x >> 1, nb = blockIdx.x & 1;
  int bm0 = mb * 64, o0 = nb * 128;
  // zero-pad A cols 48..63 (K padding)
  {
    int zr = tid >> 2, zc = 48 + (tid & 3) * 4;
    *(unsigned long long*)&Ah[zr * 72 + zc] = 0ULL;
    *(unsigned long long*)&Al[zr * 72 + zc] = 0ULL;
  }
  // stage A: 64 rows x 48 floats -> hi/lo bf16
  {
    int ar = tid >> 2, aseg = tid & 3;
    const float* Ap = phat + (size_t)(bm0 + ar) * 48 + aseg * 12;
    float4 v0 = *(const float4*)(Ap);
    float4 v1 = *(const float4*)(Ap + 4);
    float4 v2 = *(const float4*)(Ap + 8);
    float av[12] = {v0.x, v0.y, v0.z, v0.w, v1.x, v1.y, v1.z, v1.w, v2.x, v2.y, v2.z, v2.w};
    unsigned long long ph[3] = {0ULL, 0ULL, 0ULL}, pl[3] = {0ULL, 0ULL, 0ULL};
#pragma unroll
    for (int t = 0; t < 12; ++t) {
      unsigned short h = f2bf(av[t]);
      float hf = __uint_as_float(((unsigned)h) << 16);
      unsigned short l = f2bf(av[t] - hf);
      ph[t >> 2] |= ((unsigned long long)h) << ((t & 3) * 16);
      pl[t >> 2] |= ((unsigned long long)l) << ((t & 3) * 16);
    }
    int base = ar * 72 + aseg * 12;
#pragma unroll
    for (int t4 = 0; t4 < 3; ++t4) {
      *(unsigned long long*)&Ah[base + t4 * 4] = ph[t4];
      *(unsigned long long*)&Al[base + t4 * 4] = pl[t4];
    }
  }
  // stage B: 128 rows x 64 (pre-padded hi/lo bf16 from prep)
#pragma unroll
  for (int pass = 0; pass < 4; ++pass) {
    int g = pass * 2048 + tid * 8;
    int br = g >> 6, i2 = g & 63;
    short8 vh = *(const short8*)&ws1r[(size_t)(o0 + br) * 64 + i2];
    short8 vl = *(const short8*)&ws1r[16384 + (size_t)(o0 + br) * 64 + i2];
    *(short8*)&Bh[br * 72 + i2] = vh;
    *(short8*)&Bl[br * 72 + i2] = vl;
  }
  __syncthreads();
  int wid = tid >> 6, lane = tid & 63;
  int wm = wid >> 1, wn = wid & 1;
  int mh = lane & 15, quad = lane >> 4;
  f32x4 acc[2][4];
#pragma unroll
  for (int a = 0; a < 2; ++a)
#pragma unroll
    for (int bq = 0; bq < 4; ++bq) acc[a][bq] = (f32x4){0.f, 0.f, 0.f, 0.f};
#pragma unroll
  for (int kc = 0; kc < 2; ++kc) {
    int ko = kc * 32 + quad * 8;
#pragma unroll
    for (int mt = 0; mt < 2; ++mt) {
      short8 ah = *(const short8*)&Ah[(wm * 32 + mt * 16 + mh) * 72 + ko];
      short8 al = *(const short8*)&Al[(wm * 32 + mt * 16 + mh) * 72 + ko];
#pragma unroll
      for (int nt = 0; nt < 4; ++nt) {
        short8 bh = *(const short8*)&Bh[(wn * 64 + nt * 16 + mh) * 72 + ko];
        short8 bl = *(const short8*)&Bl[(wn * 64 + nt * 16 + mh) * 72 + ko];
        acc[mt][nt] = __builtin_amdgcn_mfma_f32_16x16x32_bf16(ah, bh, acc[mt][nt], 0, 0, 0);
        acc[mt][nt] = __builtin_amdgcn_mfma_f32_16x16x32_bf16(ah, bl, acc[mt][nt], 0, 0, 0);
        acc[mt][nt] = __builtin_amdgcn_mfma_f32_16x16x32_bf16(al, bh, acc[mt][nt], 0, 0, 0);
      }
    }
  }
#pragma unroll
  for (int mt = 0; mt < 2; ++mt)
#pragma unroll
    for (int nt = 0; nt < 4; ++nt) {
      int colL = wn * 64 + nt * 16 + mh;
      int col = o0 + colL;
      float bvv = bs1[col];
      float ps = 0.f, pq = 0.f;
#pragma unroll
      for (int r = 0; r < 4; ++r) {
        float val = acc[mt][nt][r] + bvv;
        pt1[(size_t)(bm0 + wm * 32 + mt * 16 + quad * 4 + r) * 256 + col] = val;
        ps += val;
        pq += val * val;
      }
      atomicAdd(&ls[colL], ps);
      atomicAdd(&ls[128 + colL], pq);
    }
  __syncthreads();
  if (tid < 128) {
    atomicAdd(&spt1[o0 + tid], ls[tid]);
    atomicAdd(&spt1[256 + o0 + tid], ls[128 + tid]);
  }
}

// ---------------- MFMA GEMM 64x128, grid 512
__global__ __launch_bounds__(256) void stn_mm_kernel(const float* __restrict__ in,
                                                     const float* __restrict__ sums,
                                                     const float* __restrict__ gg,
                                                     const float* __restrict__ be,
                                                     const float* __restrict__ W,
                                                     const float* __restrict__ bias,
                                                     float* __restrict__ out,
                                                     float* __restrict__ outstats,
                                                     int do_stats) {
  __shared__ unsigned short As[64 * 40], Bs[128 * 40];
  __shared__ float scA[256], shA[256], ls[256];
  int tid = threadIdx.x;
  ls[tid] = 0.f;
  {
    float n = (float)BM;
    float mean = sums[tid] / n;
    float var = sums[256 + tid] / n - mean * mean;
    float s = gg[tid] * rsqrtf(var + EPS);
    scA[tid] = s;
    shA[tid] = be[tid] - mean * s;
  }
  int mb = blockIdx.x >> 1, nb = blockIdx.x & 1;
  int bm0 = mb * 64, o0 = nb * 128;
  int wid = tid >> 6, lane = tid & 63;
  int wm = wid >> 1, wn = wid & 1;
  int mh = lane & 15, quad = lane >> 4;
  f32x4 acc[2][4];
#pragma unroll
  for (int a = 0; a < 2; ++a)
#pragma unroll
    for (int bq = 0; bq < 4; ++bq) acc[a][bq] = (f32x4){0.f, 0.f, 0.f, 0.f};
  int ar = tid >> 2, aseg = tid & 3;
  const float* Ag = in + (size_t)(bm0 + ar) * 256 + aseg * 8;
  int aoff = ar * 40 + aseg * 8;
  int ci = aseg * 8;
  for (int i0 = 0; i0 < 256; i0 += 32) {
    __syncthreads();
    float4 v0 = *(const float4*)(Ag + i0);
    float4 v1 = *(const float4*)(Ag + i0 + 4);
    float av[8] = {v0.x, v0.y, v0.z, v0.w, v1.x, v1.y, v1.z, v1.w};
    short8 ap;
#pragma unroll
    for (int k = 0; k < 8; ++k)
      ap[k] = (short)f2bf(fmaxf(0.f, av[k] * scA[i0 + ci + k] + shA[i0 + ci + k]));
    *(short8*)&As[aoff] = ap;
#pragma unroll
    for (int jb = 0; jb < 2; ++jb) {
      int br = jb * 64 + ar;
      const float* Bg = W + (size_t)(o0 + br) * 256 + aseg * 8;
      float4 u0 = *(const float4*)(Bg + i0);
      float4 u1 = *(const float4*)(Bg + i0 + 4);
      float bv[8] = {u0.x, u0.y, u0.z, u0.w, u1.x, u1.y, u1.z, u1.w};
      short8 bp;
#pragma unroll
      for (int k = 0; k < 8; ++k) bp[k] = (short)f2bf(bv[k]);
      *(short8*)&Bs[br * 40 + aseg * 8] = bp;
    }
    __syncthreads();
#pragma unroll
    for (int mt = 0; mt < 2; ++mt) {
      short8 af = *(const short8*)&As[(wm * 32 + mt * 16 + mh) * 40 + quad * 8];
#pragma unroll
      for (int nt = 0; nt < 4; ++nt) {
        short8 bf = *(const short8*)&Bs[(wn * 64 + nt * 16 + mh) * 40 + quad * 8];
        acc[mt][nt] = __builtin_amdgcn_mfma_f32_16x16x32_bf16(af, bf, acc[mt][nt], 0, 0, 0);
      }
    }
  }
#pragma unroll
  for (int mt = 0; mt < 2; ++mt)
#pragma unroll
    for (int nt = 0; nt < 4; ++nt) {
      int colL = wn * 64 + nt * 16 + mh;
      int col = o0 + colL;
      float bvv = bias[col];
      float ps = 0.f, pq = 0.f;
#pragma unroll
      for (int r = 0; r < 4; ++r) {
        float val = acc[mt][nt][r] + bvv;
        out[(size_t)(bm0 + wm * 32 + mt * 16 + quad * 4 + r) * 256 + col] = val;
        ps += val;
        pq += val * val;
      }
      if (do_stats) {
        atomicAdd(&ls[colL], ps);
        atomicAdd(&ls[128 + colL], pq);
      }
    }
  if (do_stats) {
    __syncthreads();
    if (tid < 128) {
      atomicAdd(&outstats[o0 + tid], ls[tid]);
      atomicAdd(&outstats[256 + o0 + tid], ls[128 + tid]);
    }
  }
}

// ---------------- h2 + T staging (phase A), transposed T-multiply (phase B)
//                  8 bm-rows per 128-thread block (grid 2048), LDS 19KB
__global__ __launch_bounds__(128) void xhat_x2_kernel(const float* __restrict__ phat,
                                                      const float* __restrict__ stats,
                                                      const float* __restrict__ stats2,
                                                      const float* __restrict__ W1,
                                                      const float* __restrict__ b1,
                                                      const float* __restrict__ g1,
                                                      const float* __restrict__ be1,
                                                      const float* __restrict__ W2,
                                                      const float* __restrict__ b2,
                                                      const float* __restrict__ g2,
                                                      const float* __restrict__ be2,
                                                      const float* __restrict__ xt,
                                                      const int* __restrict__ idx,
                                                      const float* __restrict__ Tbuf,
                                                      unsigned short* __restrict__ x2) {
  __shared__ unsigned xh[128 * 17];   // h2 bf16-pairs, stride 17 (8.5 KB)
  __shared__ float Tst[128 * TS];     // T rows, stride 20 floats (10 KB)
  __shared__ float sc1[32], sh1[32], sc2[32], sh2[32];
  int tid = threadIdx.x;  // 0..127
  if (tid < 32) {
    bn1_compute(tid, stats, W1, b1, g1, be1, &sc1[tid], &sh1[tid]);
    float n = (float)BMK;
    float mean = stats2[tid] / n;
    float var = stats2[32 + tid] / n - mean * mean;
    float s = g2[tid] * rsqrtf(var + EPS);
    sc2[tid] = s;
    sh2[tid] = be2[tid] - mean * s + b2[tid] * s;
  }
  __syncthreads();
  int bm0 = blockIdx.x * 8;           // grid 2048
  int b = bm0 >> 11;
  int bml = tid >> 4, j = tid & 15;   // bml in 0..7
  int bmk = (bm0 + bml) * 16 + j;
  // hoist pass-2 idx loads: overlap gather latency with h2 FMAs (T14)
  int jxr[16];
  {
    const int* idxrow = idx + (size_t)(bm0 + bml) * 16;
#pragma unroll
    for (int jj = 0; jj < 16; ++jj) jxr[jj] = idxrow[jj];
  }
  // ---- Phase A: thread (bml, j) computes h2 for its neighbor; stages h2 + T row
  {
    float h0 = phat[(size_t)bmk * 3], hy = phat[(size_t)bmk * 3 + 1], hz = phat[(size_t)bmk * 3 + 2];
    float h1v[32];
#pragma unroll
    for (int o = 0; o < 32; ++o) {
      float t = W1[3 * o] * h0 + W1[3 * o + 1] * hy + W1[3 * o + 2] * hz;
      h1v[o] = fmaxf(0.f, t * sc1[o] + sh1[o]);
    }
#pragma unroll
    for (int o4 = 0; o4 < 8; ++o4) {
      float r[4];
#pragma unroll
      for (int u = 0; u < 4; ++u) {
        int o = o4 * 4 + u;
        float a = 0.f;
#pragma unroll
        for (int c = 0; c < 32; ++c) a += h1v[c] * W2[o * 32 + c];
        r[u] = fmaxf(0.f, a * sc2[o] + sh2[o]);
      }
      xh[tid * 17 + o4 * 2] = (unsigned)f2bf(r[0]) | (((unsigned)f2bf(r[1])) << 16);
      xh[tid * 17 + o4 * 2 + 1] = (unsigned)f2bf(r[2]) | (((unsigned)f2bf(r[3])) << 16);
    }
    const float4* tg = (const float4*)(Tbuf + (size_t)(bm0 + bml) * 256 + j * 16);
    float4* td = (float4*)&Tst[tid * TS];
    td[0] = tg[0]; td[1] = tg[1]; td[2] = tg[2]; td[3] = tg[3];
  }
  __syncthreads();
  // ---- Phase B: thread (bml, cl) owns a channel slice; neighbors in registers
  int cl = j;  // reinterpret lane-within-group as channel-slice index
  // pass 1: h2 chunk -> u32 col cl (channels cl*2, cl*2+1)
  {
    float vlo[16], vhi[16];
#pragma unroll
    for (int jj = 0; jj < 16; ++jj) {
      unsigned uv = xh[(bml * 16 + jj) * 17 + cl];
      vlo[jj] = bf2f_lo(uv);
      vhi[jj] = bf2f_hi(uv);
    }
    for (int jo = 0; jo < 16; ++jo) {
      const float4* tr4 = (const float4*)&Tst[(bml * 16 + jo) * TS];
      float4 ta = tr4[0], tb = tr4[1], tc = tr4[2], tdd = tr4[3];
      float trow[16] = {ta.x, ta.y, ta.z, ta.w, tb.x, tb.y, tb.z, tb.w,
                        tc.x, tc.y, tc.z, tc.w, tdd.x, tdd.y, tdd.z, tdd.w};
      float a0 = 0.f, a1 = 0.f;
#pragma unroll
      for (int jj = 0; jj < 16; ++jj) {
        a0 += trow[jj] * vlo[jj];
        a1 += trow[jj] * vhi[jj];
      }
      unsigned* dst = (unsigned*)(x2 + (size_t)((bm0 + bml) * 16 + jo) * 96);
      dst[cl] = (unsigned)f2bf(a0) | (((unsigned)f2bf(a1)) << 16);
    }
  }
  // pass 2: xt chunk -> channels 32 + cl*4 .. +3 (u32 cols 16+cl*2, 17+cl*2)
  {
    float v0[16], v1[16], v2[16], v3[16];
#pragma unroll
    for (int jj = 0; jj < 16; ++jj) {
      int jx = jxr[jj];
      float4 xv = *(const float4*)(xt + ((size_t)b * Np + jx) * 64 + cl * 4);
      v0[jj] = bfround(xv.x);
      v1[jj] = bfround(xv.y);
      v2[jj] = bfround(xv.z);
      v3[jj] = bfround(xv.w);
    }
    for (int jo = 0; jo < 16; ++jo) {
      const float4* tr4 = (const float4*)&Tst[(bml * 16 + jo) * TS];
      float4 ta = tr4[0], tb = tr4[1], tc = tr4[2], tdd = tr4[3];
      float trow[16] = {ta.x, ta.y, ta.z, ta.w, tb.x, tb.y, tb.z, tb.w,
                        tc.x, tc.y, tc.z, tc.w, tdd.x, tdd.y, tdd.z, tdd.w};
      float a0 = 0.f, a1 = 0.f, a2 = 0.f, a3 = 0.f;
#pragma unroll
      for (int jj = 0; jj < 16; ++jj) {
        float t = trow[jj];
        a0 += t * v0[jj];
        a1 += t * v1[jj];
        a2 += t * v2[jj];
        a3 += t * v3[jj];
      }
      unsigned* dst = (unsigned*)(x2 + (size_t)((bm0 + bml) * 16 + jo) * 96);
      dst[16 + cl * 2] = (unsigned)f2bf(a0) | (((unsigned)f2bf(a1)) << 16);
      dst[17 + cl * 2] = (unsigned)f2bf(a2) | (((unsigned)f2bf(a3)) << 16);
    }
  }
}

// ---------------- preout = x2(bf16) @ Wcrp^T + bc, MFMA 64x128, fused stats
__global__ __launch_bounds__(256) void preout_kernel(const unsigned short* __restrict__ x2,
                                                     const unsigned short* __restrict__ Wcrp,
                                                     const float* __restrict__ bc,
                                                     float* __restrict__ pout,
                                                     float* __restrict__ spout) {
  __shared__ unsigned short As[64 * 40], Bs[128 * 40];
  __shared__ float ls[256];
  int tid = threadIdx.x;
  ls[tid] = 0.f;
  int bm0 = blockIdx.x * 64;
  int wid = tid >> 6, lane = tid & 63;
  int wm = wid >> 1, wn = wid & 1;
  int mh = lane & 15, quad = lane >> 4;
  f32x4 acc[2][4];
#pragma unroll
  for (int a = 0; a < 2; ++a)
#pragma unroll
    for (int bq = 0; bq < 4; ++bq) acc[a][bq] = (f32x4){0.f, 0.f, 0.f, 0.f};
  int ar = tid >> 2, aseg = tid & 3;
  const unsigned short* Ag = x2 + (size_t)(bm0 + ar) * 1536 + aseg * 8;
  const unsigned short* Bg0 = Wcrp + (size_t)ar * 1536 + aseg * 8;
  const unsigned short* Bg1 = Wcrp + (size_t)(64 + ar) * 1536 + aseg * 8;
  int aoff = ar * 40 + aseg * 8;
  short8 a_pre = *(const short8*)Ag;
  short8 b_pre0 = *(const short8*)Bg0;
  short8 b_pre1 = *(const short8*)Bg1;
  for (int i0 = 0; i0 < 1536; i0 += 32) {
    __syncthreads();
    *(short8*)&As[aoff] = a_pre;
    *(short8*)&Bs[aoff] = b_pre0;
    *(short8*)&Bs[64 * 40 + aoff] = b_pre1;
    __syncthreads();
    if (i0 + 32 < 1536) {
      a_pre = *(const short8*)(Ag + i0 + 32);
      b_pre0 = *(const short8*)(Bg0 + i0 + 32);
      b_pre1 = *(const short8*)(Bg1 + i0 + 32);
    }
#pragma unroll
    for (int mt = 0; mt < 2; ++mt) {
      short8 af = *(const short8*)&As[(wm * 32 + mt * 16 + mh) * 40 + quad * 8];
#pragma unroll
      for (int nt = 0; nt < 4; ++nt) {
        short8 bf = *(const short8*)&Bs[(wn * 64 + nt * 16 + mh) * 40 + quad * 8];
        acc[mt][nt] = __builtin_amdgcn_mfma_f32_16x16x32_bf16(af, bf, acc[mt][nt], 0, 0, 0);
      }
    }
  }
#pragma unroll
  for (int mt = 0; mt < 2; ++mt)
#pragma unroll
    for (int nt = 0; nt < 4; ++nt) {
      int col = wn * 64 + nt * 16 + mh;
      float bvv = bc[col];
      float ps = 0.f, pq = 0.f;
#pragma unroll
      for (int r = 0; r < 4; ++r) {
        float val = acc[mt][nt][r] + bvv;
        pout[(size_t)(bm0 + wm * 32 + mt * 16 + quad * 4 + r) * 128 + col] = val;
        ps += val;
        pq += val * val;
      }
      atomicAdd(&ls[col], ps);
      atomicAdd(&ls[128 + col], pq);
    }
  __syncthreads();
  atomicAdd(&spout[tid], ls[tid]);
}

// ---------------- epilogue: transpose+BN via LDS (q-copy moved to prep)
__global__ __launch_bounds__(256) void final_kernel(const float* __restrict__ pout,
                                                    const float* __restrict__ scs,
                                                    const float* __restrict__ gc,
                                                    const float* __restrict__ bec,
                                                    float* __restrict__ dout) {
  __shared__ float ldsT[128 * 65];
  int blk2 = blockIdx.x;
  int tid = threadIdx.x;
  int b = blk2 >> 5;
  int m0 = (blk2 & 31) * 64;
  int row = tid >> 2, seg = tid & 3;
  const float4* src = (const float4*)(pout + ((size_t)(b * Mq) + m0 + row) * 128 + seg * 32);
#pragma unroll
  for (int k4 = 0; k4 < 8; ++k4) {
    float4 v = src[k4];
    int o = seg * 32 + k4 * 4;
    ldsT[(o + 0) * 65 + row] = v.x;
    ldsT[(o + 1) * 65 + row] = v.y;
    ldsT[(o + 2) * 65 + row] = v.z;
    ldsT[(o + 3) * 65 + row] = v.w;
  }
  __syncthreads();
  int lane = tid & 63, wv = tid >> 6;
  float n = (float)BM;
  float* base = dout + (size_t)BM * 3 + (size_t)b * COUT * Mq + m0;
#pragma unroll
  for (int rep = 0; rep < 32; ++rep) {
    int o = wv * 32 + rep;
    float mean = scs[o] / n;
    float var = scs[128 + o] / n - mean * mean;
    float s = gc[o] * rsqrtf(var + EPS);
    float shv = bec[o] - mean * s;
    float v = ldsT[o * 65 + lane];
    base[(size_t)o * Mq + lane] = fmaxf(0.f, v * s + shv);
  }
}

extern "C" void kernel_launch(void* const* d_in, const int* in_sizes, int n_in, void* d_out,
                              int out_size, void* d_ws, size_t ws_size, hipStream_t stream) {
  const float* p = (const float*)d_in[0];
  const float* q = (const float*)d_in[1];
  const float* x = (const float*)d_in[2];
  const float* W1 = (const float*)d_in[3];
  const float* b1 = (const float*)d_in[4];
  const float* g1 = (const float*)d_in[5];
  const float* be1 = (const float*)d_in[6];
  const float* W2 = (const float*)d_in[7];
  const float* b2 = (const float*)d_in[8];
  const float* g2 = (const float*)d_in[9];
  const float* be2 = (const float*)d_in[10];
  const float* Ws1 = (const float*)d_in[11];
  const float* bs1 = (const float*)d_in[12];
  const float* gs1 = (const float*)d_in[13];
  const float* bes1 = (const float*)d_in[14];
  const float* Ws2 = (const float*)d_in[15];
  const float* bs2 = (const float*)d_in[16];
  const float* gs2 = (const float*)d_in[17];
  const float* bes2 = (const float*)d_in[18];
  const float* Ws3 = (const float*)d_in[19];
  const float* bs3 = (const float*)d_in[20];
  const float* Wc = (const float*)d_in[21];
  const float* bc = (const float*)d_in[22];
  const float* gc = (const float*)d_in[23];
  const float* bec = (const float*)d_in[24];
  float* dout = (float*)d_out;

  char* ws = (char*)d_ws;
  float* stats = (float*)ws;  // s1(9)@0, s2(64)@16, spt1@128, spt2@640, spout@1152
  size_t off = 8192;
  float4* pp4 = (float4*)(ws + off);  off += (size_t)Bb * Np * 16;      // 1 MB
  int* idxb = (int*)(ws + off);       off += (size_t)BMK * 4;           // 1 MB
  float* xt = (float*)(ws + off);     off += (size_t)Bb * Np * 64 * 4;  // 16 MB
  float* phat = (float*)(ws + off);   off += (size_t)BMK * 3 * 4;       // 3 MB
  float* pt1 = (float*)(ws + off);    off += (size_t)BM * 256 * 4;      // 16 MB
  float* pt2 = (float*)(ws + off);    off += (size_t)BM * 256 * 4;      // 16 MB
  float* Tb = (float*)(ws + off);     off += (size_t)BM * 256 * 4;      // 16 MB
  float* pout = (float*)(ws + off);   off += (size_t)BM * 128 * 4;      // 8 MB
  unsigned short* wcrp = (unsigned short*)(ws + off); off += (size_t)1536 * 128 * 2;
  unsigned short* x2 = (unsigned short*)(ws + off);   off += (size_t)BM * 1536 * 2;  // 48 MB
  int* hist = (int*)(ws + off);       off += (size_t)Bb * NC * 4;       // 128 KB
  int* cursor = (int*)(ws + off);     off += (size_t)Bb * NC * 4;       // 128 KB
  int* cellstart = (int*)(ws + off);  off += (size_t)Bb * (NC + 1) * 4; // ~128 KB
  float4* sp4 = (float4*)(ws + off);  off += (size_t)Bb * Np * 16;      // 1 MB
  int* sidx = (int*)(ws + off);       off += (size_t)Bb * Np * 4;       // 256 KB
  unsigned short* ws1r = (unsigned short*)(ws + off); off += (size_t)2 * 256 * 64 * 2;  // 64 KB

  hipMemsetAsync(stats, 0, 8192, stream);
  hipMemsetAsync(hist, 0, (size_t)Bb * NC * 4, stream);
  hipLaunchKernelGGL(prep_kernel, dim3(2304), dim3(256), 0, stream, p, x, Wc, Ws1, q, pp4, xt, wcrp, ws1r, hist, dout);
  hipLaunchKernelGGL(prefix_kernel, dim3(8), dim3(256), 0, stream, hist, cellstart, cursor);
  hipLaunchKernelGGL(scatter_kernel, dim3(256), dim3(256), 0, stream, pp4, cursor, sp4, sidx);
  hipLaunchKernelGGL(knn_kernel, dim3(16384), dim3(64), 0, stream, pp4, sp4, sidx, cellstart, q, idxb, phat);
  hipLaunchKernelGGL(phat_stats_kernel, dim3(256), dim3(256), 0, stream, phat, stats);
  hipLaunchKernelGGL(stn1_kernel, dim3(512), dim3(256), 0, stream, phat, ws1r, bs1, pt1, stats + 128);
  hipLaunchKernelGGL(stats2_kernel, dim3(1024), dim3(256), 0, stream, phat, stats, W1, b1, g1, be1, W2, b2, stats + 16);
  hipLaunchKernelGGL(stn_mm_kernel, dim3(512), dim3(256), 0, stream, pt1, stats + 128, gs1, bes1, Ws2, bs2, pt2, stats + 640, 1);
  hipLaunchKernelGGL(stn_mm_kernel, dim3(512), dim3(256), 0, stream, pt2, stats + 640, gs2, bes2, Ws3, bs3, Tb, (float*)nullptr, 0);
  hipLaunchKernelGGL(xhat_x2_kernel, dim3(2048), dim3(128), 0, stream, phat, stats, stats + 16,
                     W1, b1, g1, be1, W2, b2, g2, be2, xt, idxb, Tb, x2);
  hipLaunchKernelGGL(preout_kernel, dim3(256), dim3(256), 0, stream, x2, wcrp, bc, pout, stats + 1152);
  hipLaunchKernelGGL(final_kernel, dim3(256), dim3(256), 0, stream, pout, stats + 1152, gc, bec, dout);
}

// Round 16
// 351.060 us; speedup vs baseline: 1.0492x; 1.0492x over previous
//
#include <hip/hip_runtime.h>
#include <hip/hip_bf16.h>

// Round 26: REVERT of R25's flattened knn walk (regressed 49->67.5us: 6-deep
// shuffle binary-search per batch + scattered per-lane segment loads cost more
// than the lane-utilization gain). This is byte-identical to R24 (measured
// 355.9us total, knn 49.0us) — the best verified configuration.

#define EPS 1e-5f

constexpr int Bb   = 8;
constexpr int Np   = 8192;
constexpr int Mq   = 2048;
constexpr int COUT = 128;
constexpr int BM   = Bb * Mq;        // 16384
constexpr int BMK  = BM * 16;        // 262144
constexpr int GC   = 16;
constexpr int NC   = GC * GC * GC;   // 4096
constexpr int CAP  = 320;            // candidate buffer per query (8B each)
constexpr int TS   = 20;             // Tst row stride (floats); 80B, 16B-aligned

typedef __attribute__((ext_vector_type(8))) short short8;
typedef __attribute__((ext_vector_type(4))) float f32x4;

__device__ __forceinline__ unsigned short f2bf(float x) {
  unsigned u = __float_as_uint(x);
  u += 0x7fffu + ((u >> 16) & 1u);
  return (unsigned short)(u >> 16);
}
__device__ __forceinline__ float bf2f_lo(unsigned v) { return __uint_as_float(v << 16); }
__device__ __forceinline__ float bf2f_hi(unsigned v) { return __uint_as_float(v & 0xffff0000u); }
__device__ __forceinline__ float bfround(float x) {
  return __uint_as_float(((unsigned)f2bf(x)) << 16);
}

__device__ __forceinline__ int cell_of(float c) {
  int v = (int)floorf(c * 2.0f + 8.0f);
  return v < 0 ? 0 : (v > 15 ? 15 : v);
}

__device__ __forceinline__ unsigned enc_dist(float d) {
  unsigned uu = __float_as_uint(d);
  return uu ^ (((unsigned)(((int)uu) >> 31)) | 0x80000000u);
}

// ascending 64-lane bitonic sort of u64 keys
__device__ __forceinline__ void bsort64(unsigned long long& v, int lane) {
#pragma unroll
  for (int k = 2; k <= 64; k <<= 1) {
#pragma unroll
    for (int jj = k >> 1; jj > 0; jj >>= 1) {
      unsigned long long o = __shfl_xor(v, jj);
      bool keepMin = (((lane & k) == 0) == ((lane & jj) == 0));
      unsigned long long mn = v < o ? v : o;
      unsigned long long mx = v < o ? o : v;
      v = keepMin ? mn : mx;
    }
  }
}
// ascending merge of a bitonic 64-lane sequence
__device__ __forceinline__ void bmerge64(unsigned long long& v, int lane) {
#pragma unroll
  for (int jj = 32; jj > 0; jj >>= 1) {
    unsigned long long o = __shfl_xor(v, jj);
    bool keepMin = ((lane & jj) == 0);
    unsigned long long mn = v < o ? v : o;
    unsigned long long mx = v < o ? o : v;
    v = keepMin ? mn : mx;
  }
}
// sorted (ascending) smallest-64 keys of buf[0..C)
__device__ __forceinline__ unsigned long long sort_smallest64(const unsigned long long* buf,
                                                              int C, int lane) {
  unsigned long long run = (lane < C) ? buf[lane] : ~0ULL;
  bsort64(run, lane);
  for (int b2 = 64; b2 < C; b2 += 64) {
    unsigned long long v = (b2 + lane < C) ? buf[b2 + lane] : ~0ULL;
    bsort64(v, lane);
    unsigned long long vr = __shfl_xor(v, 63);  // reverse -> descending
    unsigned long long m = run < vr ? run : vr; // bitonic, contains smallest 64
    bmerge64(m, lane);
    run = m;
  }
  return run;
}

// stats float offsets: s1(9)@0, s2(64)@16, spt1(512)@128, spt2(512)@640, spout(256)@1152

__device__ __forceinline__ void bn1_compute(int o, const float* __restrict__ st,
                                            const float* __restrict__ W1,
                                            const float* __restrict__ b1,
                                            const float* __restrict__ g1,
                                            const float* __restrict__ be1,
                                            float* sc_out, float* shf_out) {
  float n = (float)BMK;
  float w0 = W1[3 * o], w1 = W1[3 * o + 1], w2 = W1[3 * o + 2], b = b1[o];
  float s0 = st[0], s1 = st[1], s2 = st[2];
  float m00 = st[3], m11 = st[4], m22 = st[5], m01 = st[6], m02 = st[7], m12 = st[8];
  float ws = (w0 * s0 + w1 * s1 + w2 * s2) / n;
  float mean = b + ws;
  float quad = w0 * w0 * m00 + w1 * w1 * m11 + w2 * w2 * m22 +
               2.f * (w0 * w1 * m01 + w0 * w2 * m02 + w1 * w2 * m12);
  float ex2 = quad / n + 2.f * b * ws + b * b;
  float var = ex2 - mean * mean;
  float sc = g1[o] * rsqrtf(var + EPS);
  *sc_out = sc;
  *shf_out = be1[o] - mean * sc + b * sc;
}

// ---------------- fused prep: pack pts (+cell histogram) | transpose x | Wc repack
//                  | Ws1 hi/lo repack | q-copy into dout
__global__ __launch_bounds__(256) void prep_kernel(const float* __restrict__ p,
                                                   const float* __restrict__ x,
                                                   const float* __restrict__ Wc,
                                                   const float* __restrict__ Ws1,
                                                   const float* __restrict__ q,
                                                   float4* __restrict__ pp4,
                                                   float* __restrict__ xt,
                                                   unsigned short* __restrict__ wcrp,
                                                   unsigned short* __restrict__ ws1r,
                                                   int* __restrict__ hist,
                                                   float* __restrict__ dout) {
  __shared__ float tile[64][65];
  int blk = blockIdx.x;
  int tid = threadIdx.x;
  if (blk < 256) {
    int i = blk * 256 + tid;  // < 65536
    float px = p[3 * i], py = p[3 * i + 1], pz = p[3 * i + 2];
    float pp = __fadd_rn(__fadd_rn(__fmul_rn(px, px), __fmul_rn(py, py)), __fmul_rn(pz, pz));
    pp4[i] = make_float4(px, py, pz, pp);
    int b = i >> 13;
    int cid = (cell_of(px) << 8) | (cell_of(py) << 4) | cell_of(pz);
    atomicAdd(&hist[b * NC + cid], 1);
  } else if (blk < 1280) {
    int bx = blk - 256;
    int b = bx >> 7;
    int n0 = (bx & 127) << 6;
    int nl = tid & 63;
    int r0 = tid >> 6;
    const float* xb = x + (size_t)b * 64 * Np;
    for (int c = r0; c < 64; c += 4) tile[c][nl] = xb[(size_t)c * Np + n0 + nl];
    __syncthreads();
    float* xtb = xt + (size_t)b * Np * 64;
    for (int n = r0; n < 64; n += 4) xtb[(size_t)(n0 + n) * 64 + nl] = tile[nl][n];
  } else if (blk < 2048) {
    int g = (blk - 1280) * 256 + tid;
    if (g < 128 * 1536) {
      int o = g / 1536, r = g % 1536;
      int c = r % 96, j = r / 96;
      wcrp[g] = f2bf(Wc[(size_t)o * 1536 + c * 16 + j]);
    }
  } else if (blk < 2112) {
    int g = (blk - 2048) * 256 + tid;  // < 16384 : (o, i) with i = k*3+c
    int o = g >> 6, i = g & 63;
    float val = 0.f;
    if (i < 48) {
      int k = i / 3, c = i - 3 * k;
      val = Ws1[(size_t)o * 48 + c * 16 + k];
    }
    unsigned short h = f2bf(val);
    float hf = __uint_as_float(((unsigned)h) << 16);
    unsigned short l = f2bf(val - hf);
    ws1r[g] = h;
    ws1r[16384 + g] = l;
  } else {
    int g = (blk - 2112) * 256 + tid;  // < 49152 = BM*3
    dout[g] = q[g];
  }
}

// ---------------- exclusive prefix over 4096 cells per batch
__global__ __launch_bounds__(256) void prefix_kernel(const int* __restrict__ hist,
                                                     int* __restrict__ cellstart,
                                                     int* __restrict__ cursor) {
  __shared__ int ls[256];
  int b = blockIdx.x, t = threadIdx.x;
  const int* h = hist + b * NC;
  int loc[16], s = 0;
#pragma unroll
  for (int k = 0; k < 16; ++k) { loc[k] = h[t * 16 + k]; s += loc[k]; }
  ls[t] = s;
  __syncthreads();
  for (int off = 1; off < 256; off <<= 1) {
    int v = (t >= off) ? ls[t - off] : 0;
    __syncthreads();
    ls[t] += v;
    __syncthreads();
  }
  int run = ls[t] - s;
  int* cs = cellstart + b * (NC + 1);
  int* cu = cursor + b * NC;
#pragma unroll
  for (int k = 0; k < 16; ++k) {
    cs[t * 16 + k] = run;
    cu[t * 16 + k] = run;
    run += loc[k];
  }
  if (t == 255) cs[NC] = run;
}

// ---------------- scatter points into cell-sorted arrays
__global__ __launch_bounds__(256) void scatter_kernel(const float4* __restrict__ pp4,
                                                      int* __restrict__ cursor,
                                                      float4* __restrict__ sp4,
                                                      int* __restrict__ sidx) {
  int i = blockIdx.x * 256 + threadIdx.x;  // < 65536
  int b = i >> 13;
  float4 pv = pp4[i];
  int cid = (cell_of(pv.x) << 8) | (cell_of(pv.y) << 4) | cell_of(pv.z);
  int pos = atomicAdd(&cursor[b * NC + cid], 1);
  sp4[(size_t)b * Np + pos] = pv;
  sidx[(size_t)b * Np + pos] = i & 8191;
}

// ---------------- kNN: one query per 64-thread block; writes idx + phat rows
__global__ __launch_bounds__(64) void knn_kernel(const float4* __restrict__ pp4,
                                                 const float4* __restrict__ sp4,
                                                 const int* __restrict__ sidx,
                                                 const int* __restrict__ cellstart,
                                                 const float* __restrict__ q,
                                                 int* __restrict__ idx_out,
                                                 float* __restrict__ phat) {
  __shared__ unsigned long long cand[CAP];  // one query per block
  int lane = threadIdx.x;
  int qi = blockIdx.x;  // 0..16383
  int b = qi >> 11;
  const float4* pb = pp4 + (size_t)b * Np;
  const float4* sp = sp4 + (size_t)b * Np;
  const int* sx = sidx + (size_t)b * Np;
  const int* cs = cellstart + b * (NC + 1);
  const float* qp = q + (size_t)qi * 3;
  float qx = qp[0], qy = qp[1], qz = qp[2];
  float qqv = __fadd_rn(__fadd_rn(__fmul_rn(qx, qx), __fmul_rn(qy, qy)), __fmul_rn(qz, qz));
  float tau_f = INFINITY;

  // ---- seed tau: smallest cell-cube with >=16 points; collect <=128 of them
  //      (center column first) into 2 regs/lane; bisect encoded-distance bits
  //      for the subset 16th -> certified upper bound on true 16th distance.
  {
    int cx = cell_of(qx), cy = cell_of(qy), cz = cell_of(qz);
    int alo = 0, blo = 0, nbw = 1, ncols = 1, zlo = 0, zhi = 0;
    int myS = 0, myE = 0;
    for (int r = 0;; ++r) {
      alo = cx - r; if (alo < 0) alo = 0;
      int ahi = cx + r; if (ahi > 15) ahi = 15;
      blo = cy - r; if (blo < 0) blo = 0;
      int bhi = cy + r; if (bhi > 15) bhi = 15;
      zlo = cz - r; if (zlo < 0) zlo = 0;
      zhi = cz + r; if (zhi > 15) zhi = 15;
      nbw = bhi - blo + 1;
      ncols = (ahi - alo + 1) * nbw;
      int total = 0;
      for (int l0 = 0; l0 < ncols; l0 += 64) {
        int l = l0 + lane;
        int sL = 0, eL = 0;
        if (l < ncols) {
          int da = l / nbw, db = l - da * nbw;
          int cbase = ((alo + da) << 8) | ((blo + db) << 4);
          sL = cs[cbase + zlo];
          eL = cs[cbase + zhi + 1];  // prefix is contiguous across z
        }
        if (l0 == 0) { myS = sL; myE = eL; }
        total += eL - sL;
      }
#pragma unroll
      for (int o = 32; o > 0; o >>= 1) total += __shfl_xor(total, o);
      if (total >= 16 || r >= 15) break;
    }
    // collect (cap 128): rotation maps global seed index g -> lane g&63, slot g>>6
    unsigned u0 = 0xFFFFFFFFu, u1 = 0xFFFFFFFFu;
    int wcnt = 0;
    int ccen = (cx - alo) * nbw + (cy - blo);
    for (int c2 = 0; c2 < ncols && wcnt < 128; ++c2) {
      int cc = (c2 == 0) ? ccen : (c2 <= ccen ? c2 - 1 : c2);
      int s0, e;
      if (cc < 64) {
        s0 = __shfl(myS, cc);
        e = __shfl(myE, cc);
      } else {  // cold: cubes wider than 64 columns
        int da = cc / nbw, db = cc - da * nbw;
        int cbase = ((alo + da) << 8) | ((blo + db) << 4);
        s0 = cs[cbase + zlo];
        e = cs[cbase + zhi + 1];
      }
      for (int off = s0; off < e && wcnt < 128; off += 64) {
        int rem = e - off; if (rem > 64) rem = 64;
        int rot = wcnt & 63;
        int rel = (lane - rot) & 63;
        int g = wcnt + rel;
        if (rel < rem && g < 128) {
          float4 pv = sp[off + rel];
          float ee = __fmaf_rn(qz, pv.z, __fmaf_rn(qy, pv.y, __fmul_rn(qx, pv.x)));
          float d = __fadd_rn(__fsub_rn(qqv, __fmul_rn(2.0f, ee)), pv.w);
          unsigned uu = enc_dist(d);
          if (g < 64) u0 = uu; else u1 = uu;
        }
        wcnt += rem;
      }
    }
    // bisection: invariant count(<= hi) >= 16 holds at EVERY iteration ->
    // hi is a certified upper bound regardless of iteration count (14 is
    // enough: residual interval < 2^19 ULP ~ <2.2% value slack).
    unsigned lo = 0u, hi = 0xFF800000u;
    for (int it = 0; it < 14; ++it) {
      unsigned mid = lo + ((hi - lo) >> 1);
      int c = (int)__popcll(__ballot(u0 <= mid)) + (int)__popcll(__ballot(u1 <= mid));
      if (c >= 16) hi = mid; else lo = mid + 1;
    }
    tau_f = (hi >= 0x80000000u) ? __uint_as_float(hi ^ 0x80000000u)
                                : __uint_as_float(~hi);
  }

  // ---- main scan: walk cells intersecting the certified ball. Candidate keys
  //      (enc_d<<32 | original idx) are order-independent -> bit-identical
  //      selection regardless of scan order.
  int cnt = 0;
  unsigned long long lanebelow = (1ULL << lane) - 1ULL;
  {
    float R = sqrtf(fmaxf(tau_f, 0.f) + 3e-5f) * 1.0005f;
    int ax0 = cell_of(qx - R), ax1 = cell_of(qx + R);
    int ay0 = cell_of(qy - R), ay1 = cell_of(qy + R);
    int az0 = cell_of(qz - R), az1 = cell_of(qz + R);
    int nby = ay1 - ay0 + 1;
    int ncols = (ax1 - ax0 + 1) * nby;
    int myS = 0, myE = 0;
    if (lane < ncols) {
      int da = lane / nby, db = lane - da * nby;
      int cbase = ((ax0 + da) << 8) | ((ay0 + db) << 4);
      myS = cs[cbase + az0];
      myE = cs[cbase + az1 + 1];
    }
    for (int cc = 0; cc < ncols; ++cc) {
      int s0, e;
      if (cc < 64) {
        s0 = __shfl(myS, cc);
        e = __shfl(myE, cc);
      } else {  // cold: spans wider than 64 columns
        int da = cc / nby, db = cc - da * nby;
        int cbase = ((ax0 + da) << 8) | ((ay0 + db) << 4);
        s0 = cs[cbase + az0];
        e = cs[cbase + az1 + 1];
      }
      for (int off = s0; off < e; off += 64) {
        int pos = off + lane;
        bool valid = pos < e;
        float4 pv = sp[valid ? pos : s0];
        float ee = __fmaf_rn(qz, pv.z, __fmaf_rn(qy, pv.y, __fmul_rn(qx, pv.x)));
        float d = __fadd_rn(__fsub_rn(qqv, __fmul_rn(2.0f, ee)), pv.w);
        if (!valid) d = __uint_as_float(0x7FC00000u);  // NaN fails d<=tau
        unsigned long long mask = __ballot(d <= tau_f);
        if (mask) {
          if (d <= tau_f) {
            int oi = sx[pos];
            unsigned uu = enc_dist(d);
            int wp = cnt + (int)__popcll(mask & lanebelow);
            if (wp < CAP)
              cand[wp] = (((unsigned long long)uu) << 32) | (unsigned)oi;
          }
          cnt += (int)__popcll(mask);
        }
      }
    }
  }

  // ---- exact selection: sorted smallest-64 of candidates; lanes 0..15 emit
  unsigned long long key16 = ~0ULL;
  if (cnt <= CAP) {
    key16 = sort_smallest64(&cand[0], cnt, lane);
  } else {
    // rare fallback: verified R11 serial-insertion scan for this query
    unsigned long long kk = ~0ULL;
    float tl = tau_f;
    for (int base = 0; base < Np; base += 64) {
      float4 pv = pb[base + lane];
      float ee = __fmaf_rn(qz, pv.z, __fmaf_rn(qy, pv.y, __fmul_rn(qx, pv.x)));
      float dv = __fadd_rn(__fsub_rn(qqv, __fmul_rn(2.0f, ee)), pv.w);
      unsigned long long mask = __ballot(dv <= tl);
      if (mask) {
        unsigned uu = enc_dist(dv);
        unsigned long long cd = (((unsigned long long)uu) << 32) | (unsigned)(base + lane);
        do {
          int src = __ffsll((unsigned long long)mask) - 1;
          mask &= mask - 1;
          unsigned long long ck = __shfl(cd, src);
          unsigned long long up = __shfl_up(kk, 1);
          if (lane == 0) up = 0ULL;
          if (lane < 16 && ck < kk) kk = (up > ck) ? up : ck;
        } while (mask);
        unsigned long long tt = __shfl(kk, 15);
        unsigned tm = (unsigned)(tt >> 32);
        unsigned inv2 = tm ^ ((tm & 0x80000000u) ? 0x80000000u : 0xFFFFFFFFu);
        float tc = (tm == 0xFFFFFFFFu) ? INFINITY : __uint_as_float(inv2);
        if (tc < tl) tl = tc;
      }
    }
    key16 = kk;
  }
  if (lane < 16) {
    int oi = (int)(key16 & 0xffffffffULL);
    idx_out[(size_t)qi * 16 + lane] = oi;
    // fused phat gather: same floats, same subtraction as old phat_stats
    float4 pv = pb[oi];
    float h0 = pv.x - qx, h1 = pv.y - qy, h2 = pv.z - qz;
    size_t base3 = ((size_t)qi * 16 + lane) * 3;
    phat[base3 + 0] = h0;
    phat[base3 + 1] = h1;
    phat[base3 + 2] = h2;
  }
}

// ---------------- accumulate 9 phat moments (linear reads; gather now in knn)
__global__ __launch_bounds__(256) void phat_stats_kernel(const float* __restrict__ phat,
                                                         float* __restrict__ stats) {
  float a[9];
#pragma unroll
  for (int k = 0; k < 9; ++k) a[k] = 0.f;
  int tid = threadIdx.x;
  for (int it = 0; it < 4; ++it) {
    int bmk = blockIdx.x * 256 + tid + it * 65536;
    float h0 = phat[(size_t)bmk * 3 + 0];
    float h1 = phat[(size_t)bmk * 3 + 1];
    float h2 = phat[(size_t)bmk * 3 + 2];
    a[0] += h0; a[1] += h1; a[2] += h2;
    a[3] += h0 * h0; a[4] += h1 * h1; a[5] += h2 * h2;
    a[6] += h0 * h1; a[7] += h0 * h2; a[8] += h1 * h2;
  }
#pragma unroll
  for (int off = 32; off > 0; off >>= 1)
#pragma unroll
    for (int k = 0; k < 9; ++k) a[k] += __shfl_down(a[k], off);
  __shared__ float ls[9];
  if (tid < 9) ls[tid] = 0.f;
  __syncthreads();
  if ((tid & 63) == 0)
    for (int k = 0; k < 9; ++k) atomicAdd(&ls[k], a[k]);
  __syncthreads();
  if (tid < 9) atomicAdd(&stats[tid], ls[tid]);
}

// ---------------- pre2 channel stats, two-phase through LDS
__global__ __launch_bounds__(256) void stats2_kernel(const float* __restrict__ phat,
                                                     const float* __restrict__ stats,
                                                     const float* __restrict__ W1,
                                                     const float* __restrict__ b1,
                                                     const float* __restrict__ g1,
                                                     const float* __restrict__ be1,
                                                     const float* __restrict__ W2,
                                                     const float* __restrict__ b2,
                                                     float* __restrict__ stats2) {
  __shared__ float hsh[256 * 36];
  __shared__ float w2s[32 * 33];
  __shared__ float w1s[96], sc1[32], sh1[32], b2s[32], ls[64];
  int tid = threadIdx.x;
  if (tid < 32) {
    bn1_compute(tid, stats, W1, b1, g1, be1, &sc1[tid], &sh1[tid]);
    b2s[tid] = b2[tid];
  }
  if (tid < 96) w1s[tid] = W1[tid];
  if (tid < 64) ls[tid] = 0.f;
  for (int e = tid; e < 1024; e += 256) w2s[(e >> 5) * 33 + (e & 31)] = W2[e];
  __syncthreads();
  {
    int bmk = blockIdx.x * 256 + tid;
    float h0 = phat[(size_t)bmk * 3], hy = phat[(size_t)bmk * 3 + 1], hz = phat[(size_t)bmk * 3 + 2];
#pragma unroll
    for (int o4 = 0; o4 < 8; ++o4) {
      float4 r;
      float* rp = (float*)&r;
#pragma unroll
      for (int u = 0; u < 4; ++u) {
        int o = o4 * 4 + u;
        float t = w1s[3 * o] * h0 + w1s[3 * o + 1] * hy + w1s[3 * o + 2] * hz;
        rp[u] = fmaxf(0.f, t * sc1[o] + sh1[o]);
      }
      *(float4*)&hsh[tid * 36 + o4 * 4] = r;
    }
  }
  __syncthreads();
  int oc = tid & 31, grp = tid >> 5;
  float wrow[32];
#pragma unroll
  for (int c = 0; c < 32; ++c) wrow[c] = w2s[oc * 33 + c];
  float bias = b2s[oc];
  float ss = 0.f, qq = 0.f;
  for (int r = 0; r < 32; ++r) {
    int row = grp * 32 + r;
    float a = bias;
    const float4* hr = (const float4*)&hsh[row * 36];
#pragma unroll
    for (int c4 = 0; c4 < 8; ++c4) {
      float4 hv = hr[c4];
      a += hv.x * wrow[c4 * 4 + 0];
      a += hv.y * wrow[c4 * 4 + 1];
      a += hv.z * wrow[c4 * 4 + 2];
      a += hv.w * wrow[c4 * 4 + 3];
    }
    ss += a;
    qq += a * a;
  }
  atomicAdd(&ls[oc], ss);
  atomicAdd(&ls[32 + oc], qq);
  __syncthreads();
  if (tid < 64) atomicAdd(&stats2[tid], ls[tid]);
}

// ---------------- stn1: pt1 = phat @ ws1r^T via bf16x2 (hi/lo) MFMA + fused stats
__global__ __launch_bounds__(256) void stn1_kernel(const float* __restrict__ phat,
                                                   const unsigned short* __restrict__ ws1r,
                                                   const float* __restrict__ bs1,
                                                   float* __restrict__ pt1,
                                                   float* __restrict__ spt1) {
  __shared__ unsigned short Ah[64 * 72], Al[64 * 72], Bh[128 * 72], Bl[128 * 72];
  __shared__ float ls[256];
  int tid = threadIdx.x;
  ls[tid] = 0.f;
  int mb = blockIdx.x >> 1, nb = blockIdx.x & 1;
  int bm0 = mb * 64, o0 = nb * 128;
  // zero-pad A cols 48..63 (K padding)
  {
    int zr = tid >> 2, zc = 48 + (tid & 3) * 4;
    *(unsigned long long*)&Ah[zr * 72 + zc] = 0ULL;
    *(unsigned long long*)&Al[zr * 72 + zc] = 0ULL;
  }
  // stage A: 64 rows x 48 floats -> hi/lo bf16
  {
    int ar = tid >> 2, aseg = tid & 3;
    const float* Ap = phat + (size_t)(bm0 + ar) * 48 + aseg * 12;
    float4 v0 = *(const float4*)(Ap);
    float4 v1 = *(const float4*)(Ap + 4);
    float4 v2 = *(const float4*)(Ap + 8);
    float av[12] = {v0.x, v0.y, v0.z, v0.w, v1.x, v1.y, v1.z, v1.w, v2.x, v2.y, v2.z, v2.w};
    unsigned long long ph[3] = {0ULL, 0ULL, 0ULL}, pl[3] = {0ULL, 0ULL, 0ULL};
#pragma unroll
    for (int t = 0; t < 12; ++t) {
      unsigned short h = f2bf(av[t]);
      float hf = __uint_as_float(((unsigned)h) << 16);
      unsigned short l = f2bf(av[t] - hf);
      ph[t >> 2] |= ((unsigned long long)h) << ((t & 3) * 16);
      pl[t >> 2] |= ((unsigned long long)l) << ((t & 3) * 16);
    }
    int base = ar * 72 + aseg * 12;
#pragma unroll
    for (int t4 = 0; t4 < 3; ++t4) {
      *(unsigned long long*)&Ah[base + t4 * 4] = ph[t4];
      *(unsigned long long*)&Al[base + t4 * 4] = pl[t4];
    }
  }
  // stage B: 128 rows x 64 (pre-padded hi/lo bf16 from prep)
#pragma unroll
  for (int pass = 0; pass < 4; ++pass) {
    int g = pass * 2048 + tid * 8;
    int br = g >> 6, i2 = g & 63;
    short8 vh = *(const short8*)&ws1r[(size_t)(o0 + br) * 64 + i2];
    short8 vl = *(const short8*)&ws1r[16384 + (size_t)(o0 + br) * 64 + i2];
    *(short8*)&Bh[br * 72 + i2] = vh;
    *(short8*)&Bl[br * 72 + i2] = vl;
  }
  __syncthreads();
  int wid = tid >> 6, lane = tid & 63;
  int wm = wid >> 1, wn = wid & 1;
  int mh = lane & 15, quad = lane >> 4;
  f32x4 acc[2][4];
#pragma unroll
  for (int a = 0; a < 2; ++a)
#pragma unroll
    for (int bq = 0; bq < 4; ++bq) acc[a][bq] = (f32x4){0.f, 0.f, 0.f, 0.f};
#pragma unroll
  for (int kc = 0; kc < 2; ++kc) {
    int ko = kc * 32 + quad * 8;
#pragma unroll
    for (int mt = 0; mt < 2; ++mt) {
      short8 ah = *(const short8*)&Ah[(wm * 32 + mt * 16 + mh) * 72 + ko];
      short8 al = *(const short8*)&Al[(wm * 32 + mt * 16 + mh) * 72 + ko];
#pragma unroll
      for (int nt = 0; nt < 4; ++nt) {
        short8 bh = *(const short8*)&Bh[(wn * 64 + nt * 16 + mh) * 72 + ko];
        short8 bl = *(const short8*)&Bl[(wn * 64 + nt * 16 + mh) * 72 + ko];
        acc[mt][nt] = __builtin_amdgcn_mfma_f32_16x16x32_bf16(ah, bh, acc[mt][nt], 0, 0, 0);
        acc[mt][nt] = __builtin_amdgcn_mfma_f32_16x16x32_bf16(ah, bl, acc[mt][nt], 0, 0, 0);
        acc[mt][nt] = __builtin_amdgcn_mfma_f32_16x16x32_bf16(al, bh, acc[mt][nt], 0, 0, 0);
      }
    }
  }
#pragma unroll
  for (int mt = 0; mt < 2; ++mt)
#pragma unroll
    for (int nt = 0; nt < 4; ++nt) {
      int colL = wn * 64 + nt * 16 + mh;
      int col = o0 + colL;
      float bvv = bs1[col];
      float ps = 0.f, pq = 0.f;
#pragma unroll
      for (int r = 0; r < 4; ++r) {
        float val = acc[mt][nt][r] + bvv;
        pt1[(size_t)(bm0 + wm * 32 + mt * 16 + quad * 4 + r) * 256 + col] = val;
        ps += val;
        pq += val * val;
      }
      atomicAdd(&ls[colL], ps);
      atomicAdd(&ls[128 + colL], pq);
    }
  __syncthreads();
  if (tid < 128) {
    atomicAdd(&spt1[o0 + tid], ls[tid]);
    atomicAdd(&spt1[256 + o0 + tid], ls[128 + tid]);
  }
}

// ---------------- MFMA GEMM 64x128, grid 512
__global__ __launch_bounds__(256) void stn_mm_kernel(const float* __restrict__ in,
                                                     const float* __restrict__ sums,
                                                     const float* __restrict__ gg,
                                                     const float* __restrict__ be,
                                                     const float* __restrict__ W,
                                                     const float* __restrict__ bias,
                                                     float* __restrict__ out,
                                                     float* __restrict__ outstats,
                                                     int do_stats) {
  __shared__ unsigned short As[64 * 40], Bs[128 * 40];
  __shared__ float scA[256], shA[256], ls[256];
  int tid = threadIdx.x;
  ls[tid] = 0.f;
  {
    float n = (float)BM;
    float mean = sums[tid] / n;
    float var = sums[256 + tid] / n - mean * mean;
    float s = gg[tid] * rsqrtf(var + EPS);
    scA[tid] = s;
    shA[tid] = be[tid] - mean * s;
  }
  int mb = blockIdx.x >> 1, nb = blockIdx.x & 1;
  int bm0 = mb * 64, o0 = nb * 128;
  int wid = tid >> 6, lane = tid & 63;
  int wm = wid >> 1, wn = wid & 1;
  int mh = lane & 15, quad = lane >> 4;
  f32x4 acc[2][4];
#pragma unroll
  for (int a = 0; a < 2; ++a)
#pragma unroll
    for (int bq = 0; bq < 4; ++bq) acc[a][bq] = (f32x4){0.f, 0.f, 0.f, 0.f};
  int ar = tid >> 2, aseg = tid & 3;
  const float* Ag = in + (size_t)(bm0 + ar) * 256 + aseg * 8;
  int aoff = ar * 40 + aseg * 8;
  int ci = aseg * 8;
  for (int i0 = 0; i0 < 256; i0 += 32) {
    __syncthreads();
    float4 v0 = *(const float4*)(Ag + i0);
    float4 v1 = *(const float4*)(Ag + i0 + 4);
    float av[8] = {v0.x, v0.y, v0.z, v0.w, v1.x, v1.y, v1.z, v1.w};
    short8 ap;
#pragma unroll
    for (int k = 0; k < 8; ++k)
      ap[k] = (short)f2bf(fmaxf(0.f, av[k] * scA[i0 + ci + k] + shA[i0 + ci + k]));
    *(short8*)&As[aoff] = ap;
#pragma unroll
    for (int jb = 0; jb < 2; ++jb) {
      int br = jb * 64 + ar;
      const float* Bg = W + (size_t)(o0 + br) * 256 + aseg * 8;
      float4 u0 = *(const float4*)(Bg + i0);
      float4 u1 = *(const float4*)(Bg + i0 + 4);
      float bv[8] = {u0.x, u0.y, u0.z, u0.w, u1.x, u1.y, u1.z, u1.w};
      short8 bp;
#pragma unroll
      for (int k = 0; k < 8; ++k) bp[k] = (short)f2bf(bv[k]);
      *(short8*)&Bs[br * 40 + aseg * 8] = bp;
    }
    __syncthreads();
#pragma unroll
    for (int mt = 0; mt < 2; ++mt) {
      short8 af = *(const short8*)&As[(wm * 32 + mt * 16 + mh) * 40 + quad * 8];
#pragma unroll
      for (int nt = 0; nt < 4; ++nt) {
        short8 bf = *(const short8*)&Bs[(wn * 64 + nt * 16 + mh) * 40 + quad * 8];
        acc[mt][nt] = __builtin_amdgcn_mfma_f32_16x16x32_bf16(af, bf, acc[mt][nt], 0, 0, 0);
      }
    }
  }
#pragma unroll
  for (int mt = 0; mt < 2; ++mt)
#pragma unroll
    for (int nt = 0; nt < 4; ++nt) {
      int colL = wn * 64 + nt * 16 + mh;
      int col = o0 + colL;
      float bvv = bias[col];
      float ps = 0.f, pq = 0.f;
#pragma unroll
      for (int r = 0; r < 4; ++r) {
        float val = acc[mt][nt][r] + bvv;
        out[(size_t)(bm0 + wm * 32 + mt * 16 + quad * 4 + r) * 256 + col] = val;
        ps += val;
        pq += val * val;
      }
      if (do_stats) {
        atomicAdd(&ls[colL], ps);
        atomicAdd(&ls[128 + colL], pq);
      }
    }
  if (do_stats) {
    __syncthreads();
    if (tid < 128) {
      atomicAdd(&outstats[o0 + tid], ls[tid]);
      atomicAdd(&outstats[256 + o0 + tid], ls[128 + tid]);
    }
  }
}

// ---------------- h2 + T staging (phase A), transposed T-multiply (phase B)
//                  8 bm-rows per 128-thread block (grid 2048), LDS 19KB
__global__ __launch_bounds__(128) void xhat_x2_kernel(const float* __restrict__ phat,
                                                      const float* __restrict__ stats,
                                                      const float* __restrict__ stats2,
                                                      const float* __restrict__ W1,
                                                      const float* __restrict__ b1,
                                                      const float* __restrict__ g1,
                                                      const float* __restrict__ be1,
                                                      const float* __restrict__ W2,
                                                      const float* __restrict__ b2,
                                                      const float* __restrict__ g2,
                                                      const float* __restrict__ be2,
                                                      const float* __restrict__ xt,
                                                      const int* __restrict__ idx,
                                                      const float* __restrict__ Tbuf,
                                                      unsigned short* __restrict__ x2) {
  __shared__ unsigned xh[128 * 17];   // h2 bf16-pairs, stride 17 (8.5 KB)
  __shared__ float Tst[128 * TS];     // T rows, stride 20 floats (10 KB)
  __shared__ float sc1[32], sh1[32], sc2[32], sh2[32];
  int tid = threadIdx.x;  // 0..127
  if (tid < 32) {
    bn1_compute(tid, stats, W1, b1, g1, be1, &sc1[tid], &sh1[tid]);
    float n = (float)BMK;
    float mean = stats2[tid] / n;
    float var = stats2[32 + tid] / n - mean * mean;
    float s = g2[tid] * rsqrtf(var + EPS);
    sc2[tid] = s;
    sh2[tid] = be2[tid] - mean * s + b2[tid] * s;
  }
  __syncthreads();
  int bm0 = blockIdx.x * 8;           // grid 2048
  int b = bm0 >> 11;
  int bml = tid >> 4, j = tid & 15;   // bml in 0..7
  int bmk = (bm0 + bml) * 16 + j;
  // hoist pass-2 idx loads: overlap gather latency with h2 FMAs (T14)
  int jxr[16];
  {
    const int* idxrow = idx + (size_t)(bm0 + bml) * 16;
#pragma unroll
    for (int jj = 0; jj < 16; ++jj) jxr[jj] = idxrow[jj];
  }
  // ---- Phase A: thread (bml, j) computes h2 for its neighbor; stages h2 + T row
  {
    float h0 = phat[(size_t)bmk * 3], hy = phat[(size_t)bmk * 3 + 1], hz = phat[(size_t)bmk * 3 + 2];
    float h1v[32];
#pragma unroll
    for (int o = 0; o < 32; ++o) {
      float t = W1[3 * o] * h0 + W1[3 * o + 1] * hy + W1[3 * o + 2] * hz;
      h1v[o] = fmaxf(0.f, t * sc1[o] + sh1[o]);
    }
#pragma unroll
    for (int o4 = 0; o4 < 8; ++o4) {
      float r[4];
#pragma unroll
      for (int u = 0; u < 4; ++u) {
        int o = o4 * 4 + u;
        float a = 0.f;
#pragma unroll
        for (int c = 0; c < 32; ++c) a += h1v[c] * W2[o * 32 + c];
        r[u] = fmaxf(0.f, a * sc2[o] + sh2[o]);
      }
      xh[tid * 17 + o4 * 2] = (unsigned)f2bf(r[0]) | (((unsigned)f2bf(r[1])) << 16);
      xh[tid * 17 + o4 * 2 + 1] = (unsigned)f2bf(r[2]) | (((unsigned)f2bf(r[3])) << 16);
    }
    const float4* tg = (const float4*)(Tbuf + (size_t)(bm0 + bml) * 256 + j * 16);
    float4* td = (float4*)&Tst[tid * TS];
    td[0] = tg[0]; td[1] = tg[1]; td[2] = tg[2]; td[3] = tg[3];
  }
  __syncthreads();
  // ---- Phase B: thread (bml, cl) owns a channel slice; neighbors in registers
  int cl = j;  // reinterpret lane-within-group as channel-slice index
  // pass 1: h2 chunk -> u32 col cl (channels cl*2, cl*2+1)
  {
    float vlo[16], vhi[16];
#pragma unroll
    for (int jj = 0; jj < 16; ++jj) {
      unsigned uv = xh[(bml * 16 + jj) * 17 + cl];
      vlo[jj] = bf2f_lo(uv);
      vhi[jj] = bf2f_hi(uv);
    }
    for (int jo = 0; jo < 16; ++jo) {
      const float4* tr4 = (const float4*)&Tst[(bml * 16 + jo) * TS];
      float4 ta = tr4[0], tb = tr4[1], tc = tr4[2], tdd = tr4[3];
      float trow[16] = {ta.x, ta.y, ta.z, ta.w, tb.x, tb.y, tb.z, tb.w,
                        tc.x, tc.y, tc.z, tc.w, tdd.x, tdd.y, tdd.z, tdd.w};
      float a0 = 0.f, a1 = 0.f;
#pragma unroll
      for (int jj = 0; jj < 16; ++jj) {
        a0 += trow[jj] * vlo[jj];
        a1 += trow[jj] * vhi[jj];
      }
      unsigned* dst = (unsigned*)(x2 + (size_t)((bm0 + bml) * 16 + jo) * 96);
      dst[cl] = (unsigned)f2bf(a0) | (((unsigned)f2bf(a1)) << 16);
    }
  }
  // pass 2: xt chunk -> channels 32 + cl*4 .. +3 (u32 cols 16+cl*2, 17+cl*2)
  {
    float v0[16], v1[16], v2[16], v3[16];
#pragma unroll
    for (int jj = 0; jj < 16; ++jj) {
      int jx = jxr[jj];
      float4 xv = *(const float4*)(xt + ((size_t)b * Np + jx) * 64 + cl * 4);
      v0[jj] = bfround(xv.x);
      v1[jj] = bfround(xv.y);
      v2[jj] = bfround(xv.z);
      v3[jj] = bfround(xv.w);
    }
    for (int jo = 0; jo < 16; ++jo) {
      const float4* tr4 = (const float4*)&Tst[(bml * 16 + jo) * TS];
      float4 ta = tr4[0], tb = tr4[1], tc = tr4[2], tdd = tr4[3];
      float trow[16] = {ta.x, ta.y, ta.z, ta.w, tb.x, tb.y, tb.z, tb.w,
                        tc.x, tc.y, tc.z, tc.w, tdd.x, tdd.y, tdd.z, tdd.w};
      float a0 = 0.f, a1 = 0.f, a2 = 0.f, a3 = 0.f;
#pragma unroll
      for (int jj = 0; jj < 16; ++jj) {
        float t = trow[jj];
        a0 += t * v0[jj];
        a1 += t * v1[jj];
        a2 += t * v2[jj];
        a3 += t * v3[jj];
      }
      unsigned* dst = (unsigned*)(x2 + (size_t)((bm0 + bml) * 16 + jo) * 96);
      dst[16 + cl * 2] = (unsigned)f2bf(a0) | (((unsigned)f2bf(a1)) << 16);
      dst[17 + cl * 2] = (unsigned)f2bf(a2) | (((unsigned)f2bf(a3)) << 16);
    }
  }
}

// ---------------- preout = x2(bf16) @ Wcrp^T + bc, MFMA 64x128, fused stats
__global__ __launch_bounds__(256) void preout_kernel(const unsigned short* __restrict__ x2,
                                                     const unsigned short* __restrict__ Wcrp,
                                                     const float* __restrict__ bc,
                                                     float* __restrict__ pout,
                                                     float* __restrict__ spout) {
  __shared__ unsigned short As[64 * 40], Bs[128 * 40];
  __shared__ float ls[256];
  int tid = threadIdx.x;
  ls[tid] = 0.f;
  int bm0 = blockIdx.x * 64;
  int wid = tid >> 6, lane = tid & 63;
  int wm = wid >> 1, wn = wid & 1;
  int mh = lane & 15, quad = lane >> 4;
  f32x4 acc[2][4];
#pragma unroll
  for (int a = 0; a < 2; ++a)
#pragma unroll
    for (int bq = 0; bq < 4; ++bq) acc[a][bq] = (f32x4){0.f, 0.f, 0.f, 0.f};
  int ar = tid >> 2, aseg = tid & 3;
  const unsigned short* Ag = x2 + (size_t)(bm0 + ar) * 1536 + aseg * 8;
  const unsigned short* Bg0 = Wcrp + (size_t)ar * 1536 + aseg * 8;
  const unsigned short* Bg1 = Wcrp + (size_t)(64 + ar) * 1536 + aseg * 8;
  int aoff = ar * 40 + aseg * 8;
  short8 a_pre = *(const short8*)Ag;
  short8 b_pre0 = *(const short8*)Bg0;
  short8 b_pre1 = *(const short8*)Bg1;
  for (int i0 = 0; i0 < 1536; i0 += 32) {
    __syncthreads();
    *(short8*)&As[aoff] = a_pre;
    *(short8*)&Bs[aoff] = b_pre0;
    *(short8*)&Bs[64 * 40 + aoff] = b_pre1;
    __syncthreads();
    if (i0 + 32 < 1536) {
      a_pre = *(const short8*)(Ag + i0 + 32);
      b_pre0 = *(const short8*)(Bg0 + i0 + 32);
      b_pre1 = *(const short8*)(Bg1 + i0 + 32);
    }
#pragma unroll
    for (int mt = 0; mt < 2; ++mt) {
      short8 af = *(const short8*)&As[(wm * 32 + mt * 16 + mh) * 40 + quad * 8];
#pragma unroll
      for (int nt = 0; nt < 4; ++nt) {
        short8 bf = *(const short8*)&Bs[(wn * 64 + nt * 16 + mh) * 40 + quad * 8];
        acc[mt][nt] = __builtin_amdgcn_mfma_f32_16x16x32_bf16(af, bf, acc[mt][nt], 0, 0, 0);
      }
    }
  }
#pragma unroll
  for (int mt = 0; mt < 2; ++mt)
#pragma unroll
    for (int nt = 0; nt < 4; ++nt) {
      int col = wn * 64 + nt * 16 + mh;
      float bvv = bc[col];
      float ps = 0.f, pq = 0.f;
#pragma unroll
      for (int r = 0; r < 4; ++r) {
        float val = acc[mt][nt][r] + bvv;
        pout[(size_t)(bm0 + wm * 32 + mt * 16 + quad * 4 + r) * 128 + col] = val;
        ps += val;
        pq += val * val;
      }
      atomicAdd(&ls[col], ps);
      atomicAdd(&ls[128 + col], pq);
    }
  __syncthreads();
  atomicAdd(&spout[tid], ls[tid]);
}

// ---------------- epilogue: transpose+BN via LDS (q-copy moved to prep)
__global__ __launch_bounds__(256) void final_kernel(const float* __restrict__ pout,
                                                    const float* __restrict__ scs,
                                                    const float* __restrict__ gc,
                                                    const float* __restrict__ bec,
                                                    float* __restrict__ dout) {
  __shared__ float ldsT[128 * 65];
  int blk2 = blockIdx.x;
  int tid = threadIdx.x;
  int b = blk2 >> 5;
  int m0 = (blk2 & 31) * 64;
  int row = tid >> 2, seg = tid & 3;
  const float4* src = (const float4*)(pout + ((size_t)(b * Mq) + m0 + row) * 128 + seg * 32);
#pragma unroll
  for (int k4 = 0; k4 < 8; ++k4) {
    float4 v = src[k4];
    int o = seg * 32 + k4 * 4;
    ldsT[(o + 0) * 65 + row] = v.x;
    ldsT[(o + 1) * 65 + row] = v.y;
    ldsT[(o + 2) * 65 + row] = v.z;
    ldsT[(o + 3) * 65 + row] = v.w;
  }
  __syncthreads();
  int lane = tid & 63, wv = tid >> 6;
  float n = (float)BM;
  float* base = dout + (size_t)BM * 3 + (size_t)b * COUT * Mq + m0;
#pragma unroll
  for (int rep = 0; rep < 32; ++rep) {
    int o = wv * 32 + rep;
    float mean = scs[o] / n;
    float var = scs[128 + o] / n - mean * mean;
    float s = gc[o] * rsqrtf(var + EPS);
    float shv = bec[o] - mean * s;
    float v = ldsT[o * 65 + lane];
    base[(size_t)o * Mq + lane] = fmaxf(0.f, v * s + shv);
  }
}

extern "C" void kernel_launch(void* const* d_in, const int* in_sizes, int n_in, void* d_out,
                              int out_size, void* d_ws, size_t ws_size, hipStream_t stream) {
  const float* p = (const float*)d_in[0];
  const float* q = (const float*)d_in[1];
  const float* x = (const float*)d_in[2];
  const float* W1 = (const float*)d_in[3];
  const float* b1 = (const float*)d_in[4];
  const float* g1 = (const float*)d_in[5];
  const float* be1 = (const float*)d_in[6];
  const float* W2 = (const float*)d_in[7];
  const float* b2 = (const float*)d_in[8];
  const float* g2 = (const float*)d_in[9];
  const float* be2 = (const float*)d_in[10];
  const float* Ws1 = (const float*)d_in[11];
  const float* bs1 = (const float*)d_in[12];
  const float* gs1 = (const float*)d_in[13];
  const float* bes1 = (const float*)d_in[14];
  const float* Ws2 = (const float*)d_in[15];
  const float* bs2 = (const float*)d_in[16];
  const float* gs2 = (const float*)d_in[17];
  const float* bes2 = (const float*)d_in[18];
  const float* Ws3 = (const float*)d_in[19];
  const float* bs3 = (const float*)d_in[20];
  const float* Wc = (const float*)d_in[21];
  const float* bc = (const float*)d_in[22];
  const float* gc = (const float*)d_in[23];
  const float* bec = (const float*)d_in[24];
  float* dout = (float*)d_out;

  char* ws = (char*)d_ws;
  float* stats = (float*)ws;  // s1(9)@0, s2(64)@16, spt1@128, spt2@640, spout@1152
  size_t off = 8192;
  float4* pp4 = (float4*)(ws + off);  off += (size_t)Bb * Np * 16;      // 1 MB
  int* idxb = (int*)(ws + off);       off += (size_t)BMK * 4;           // 1 MB
  float* xt = (float*)(ws + off);     off += (size_t)Bb * Np * 64 * 4;  // 16 MB
  float* phat = (float*)(ws + off);   off += (size_t)BMK * 3 * 4;       // 3 MB
  float* pt1 = (float*)(ws + off);    off += (size_t)BM * 256 * 4;      // 16 MB
  float* pt2 = (float*)(ws + off);    off += (size_t)BM * 256 * 4;      // 16 MB
  float* Tb = (float*)(ws + off);     off += (size_t)BM * 256 * 4;      // 16 MB
  float* pout = (float*)(ws + off);   off += (size_t)BM * 128 * 4;      // 8 MB
  unsigned short* wcrp = (unsigned short*)(ws + off); off += (size_t)1536 * 128 * 2;
  unsigned short* x2 = (unsigned short*)(ws + off);   off += (size_t)BM * 1536 * 2;  // 48 MB
  int* hist = (int*)(ws + off);       off += (size_t)Bb * NC * 4;       // 128 KB
  int* cursor = (int*)(ws + off);     off += (size_t)Bb * NC * 4;       // 128 KB
  int* cellstart = (int*)(ws + off);  off += (size_t)Bb * (NC + 1) * 4; // ~128 KB
  float4* sp4 = (float4*)(ws + off);  off += (size_t)Bb * Np * 16;      // 1 MB
  int* sidx = (int*)(ws + off);       off += (size_t)Bb * Np * 4;       // 256 KB
  unsigned short* ws1r = (unsigned short*)(ws + off); off += (size_t)2 * 256 * 64 * 2;  // 64 KB

  hipMemsetAsync(stats, 0, 8192, stream);
  hipMemsetAsync(hist, 0, (size_t)Bb * NC * 4, stream);
  hipLaunchKernelGGL(prep_kernel, dim3(2304), dim3(256), 0, stream, p, x, Wc, Ws1, q, pp4, xt, wcrp, ws1r, hist, dout);
  hipLaunchKernelGGL(prefix_kernel, dim3(8), dim3(256), 0, stream, hist, cellstart, cursor);
  hipLaunchKernelGGL(scatter_kernel, dim3(256), dim3(256), 0, stream, pp4, cursor, sp4, sidx);
  hipLaunchKernelGGL(knn_kernel, dim3(16384), dim3(64), 0, stream, pp4, sp4, sidx, cellstart, q, idxb, phat);
  hipLaunchKernelGGL(phat_stats_kernel, dim3(256), dim3(256), 0, stream, phat, stats);
  hipLaunchKernelGGL(stn1_kernel, dim3(512), dim3(256), 0, stream, phat, ws1r, bs1, pt1, stats + 128);
  hipLaunchKernelGGL(stats2_kernel, dim3(1024), dim3(256), 0, stream, phat, stats, W1, b1, g1, be1, W2, b2, stats + 16);
  hipLaunchKernelGGL(stn_mm_kernel, dim3(512), dim3(256), 0, stream, pt1, stats + 128, gs1, bes1, Ws2, bs2, pt2, stats + 640, 1);
  hipLaunchKernelGGL(stn_mm_kernel, dim3(512), dim3(256), 0, stream, pt2, stats + 640, gs2, bes2, Ws3, bs3, Tb, (float*)nullptr, 0);
  hipLaunchKernelGGL(xhat_x2_kernel, dim3(2048), dim3(128), 0, stream, phat, stats, stats + 16,
                     W1, b1, g1, be1, W2, b2, g2, be2, xt, idxb, Tb, x2);
  hipLaunchKernelGGL(preout_kernel, dim3(256), dim3(256), 0, stream, x2, wcrp, bc, pout, stats + 1152);
  hipLaunchKernelGGL(final_kernel, dim3(256), dim3(256), 0, stream, pout, stats + 1152, gc, bec, dout);
}